// Round 13
// baseline (401.326 us; speedup 1.0000x reference)
//
#include <hip/hip_runtime.h>
#include <hip/hip_fp16.h>
#include <stdint.h>

#define NEG_SLOPE 0.2f
#define BSHIFT 7          // bucket = dst >> 7  (128 dsts per bucket)
#define NB 256            // blocks in bucket hist/scatter passes

__device__ __forceinline__ float lrelu(float x){ return x > 0.f ? x : NEG_SLOPE * x; }
__device__ __forceinline__ float elu1(float x){ return x > 0.f ? x : expm1f(x); }
// float -> ordered uint encoding for atomicMax over signed floats
__device__ __forceinline__ unsigned fenc(float f){
  unsigned u = __float_as_uint(f);
  return (u & 0x80000000u) ? ~u : (u | 0x80000000u);
}
__device__ __forceinline__ float fdec(unsigned u){
  return (u & 0x80000000u) ? __uint_as_float(u & 0x7fffffffu) : __uint_as_float(~u);
}

// Fused: blocks [0,G) = h1 GEMM (128x128 tile, 8x8 reg tile);
//        blocks [G,G+NB) = per-block dst-bucket histogram (independent inputs).
__global__ __launch_bounds__(256) void k_gemm1_hist(
    const float* __restrict__ x, const float* __restrict__ W1,
    const float* __restrict__ atts, const float* __restrict__ attd,
    __half* __restrict__ h1, float* __restrict__ as1, float* __restrict__ ad1,
    float* __restrict__ gblkmax,
    const int* __restrict__ ei, int* __restrict__ gcnt,
    int E, int N, int B, int chunk, int G){
  __shared__ float xs[128 * 128];   // 64 KB exactly (hist part reuses prefix)
  if (blockIdx.x >= G){
    // ---- histogram part ----
    int bid = blockIdx.x - G;
    int* hist = (int*)xs;           // first 512 ints
    for (int t = threadIdx.x; t < B; t += 256) hist[t] = 0;
    __syncthreads();
    int T = E + N;
    int lo = bid * chunk;
    int hi = min(lo + chunk, T);
    for (int i = lo + (int)threadIdx.x; i < hi; i += 256){
      int d = (i < E) ? ei[E + i] : (i - E);
      atomicAdd(&hist[d >> BSHIFT], 1);
    }
    __syncthreads();
    for (int t = threadIdx.x; t < B; t += 256) gcnt[bid * B + t] = hist[t];
    return;
  }
  // ---- GEMM part ----
  int n0 = blockIdx.x * 128;
  int t = threadIdx.x;
  {
    int row = t & 127;
    int kc = t >> 7;                // 0 or 1 (k-half)
    int n = n0 + row;
    const float4* x4 = (const float4*)x;
    #pragma unroll 4
    for (int i = 0; i < 16; ++i){
      float4 v = (n < N) ? x4[(size_t)n * 32 + kc * 16 + i]
                         : make_float4(0.f, 0.f, 0.f, 0.f);
      int k = kc * 64 + 4 * i;
      xs[(k + 0) * 128 + row] = v.x;
      xs[(k + 1) * 128 + row] = v.y;
      xs[(k + 2) * 128 + row] = v.z;
      xs[(k + 3) * 128 + row] = v.w;
    }
  }
  __syncthreads();
  int m = t & 15;                 // cols 8m..8m+7
  int rg = t >> 4;                // rows 8rg..8rg+7
  int rb = rg * 8;
  const float4* W14 = (const float4*)W1;
  float acc[8][8];
  #pragma unroll
  for (int r = 0; r < 8; ++r)
    #pragma unroll
    for (int c = 0; c < 8; ++c) acc[r][c] = 0.f;
  #pragma unroll 2
  for (int k = 0; k < 128; ++k){
    float4 w0 = W14[k * 32 + 2 * m];
    float4 w1 = W14[k * 32 + 2 * m + 1];
    float4 xa = *(const float4*)&xs[k * 128 + rb];
    float4 xb = *(const float4*)&xs[k * 128 + rb + 4];
    float xr[8] = {xa.x, xa.y, xa.z, xa.w, xb.x, xb.y, xb.z, xb.w};
    float wc[8] = {w0.x, w0.y, w0.z, w0.w, w1.x, w1.y, w1.z, w1.w};
    #pragma unroll
    for (int r = 0; r < 8; ++r)
      #pragma unroll
      for (int c = 0; c < 8; ++c)
        acc[r][c] = fmaf(xr[r], wc[c], acc[r][c]);
  }
  float4 av0 = ((const float4*)atts)[2 * m], av1 = ((const float4*)atts)[2 * m + 1];
  float4 dv0 = ((const float4*)attd)[2 * m], dv1 = ((const float4*)attd)[2 * m + 1];
  int h = m >> 2;                 // head of cols 8m..8m+7
  float lmax = -INFINITY;
  #pragma unroll
  for (int r = 0; r < 8; ++r){
    int n = n0 + rb + r;
    if (n < N){
      union { __half2 hh[4]; float4 f; } u;
      u.hh[0] = __floats2half2_rn(acc[r][0], acc[r][1]);
      u.hh[1] = __floats2half2_rn(acc[r][2], acc[r][3]);
      u.hh[2] = __floats2half2_rn(acc[r][4], acc[r][5]);
      u.hh[3] = __floats2half2_rn(acc[r][6], acc[r][7]);
      *(float4*)(h1 + (size_t)n * 128 + 8 * m) = u.f;
    }
    float s  = acc[r][0]*av0.x + acc[r][1]*av0.y + acc[r][2]*av0.z + acc[r][3]*av0.w
             + acc[r][4]*av1.x + acc[r][5]*av1.y + acc[r][6]*av1.z + acc[r][7]*av1.w;
    float dd = acc[r][0]*dv0.x + acc[r][1]*dv0.y + acc[r][2]*dv0.z + acc[r][3]*dv0.w
             + acc[r][4]*dv1.x + acc[r][5]*dv1.y + acc[r][6]*dv1.z + acc[r][7]*dv1.w;
    s  += __shfl_down(s, 1);  s  += __shfl_down(s, 2);
    dd += __shfl_down(dd, 1); dd += __shfl_down(dd, 2);
    lmax = fmaxf(lmax, s);
    if ((m & 3) == 0 && n < N){
      as1[n * 4 + h] = s;
      ad1[n * 4 + h] = dd;
    }
  }
  // per-block head max -> gblkmax[blk*4+h]  (reuse xs after all reads done)
  __syncthreads();
  if ((m & 3) == 0) xs[(m >> 2) * 16 + rg] = lmax;
  __syncthreads();
  if (t < 4){
    float mx = xs[t * 16];
    #pragma unroll
    for (int i = 1; i < 16; ++i) mx = fmaxf(mx, xs[t * 16 + i]);
    gblkmax[blockIdx.x * 4 + t] = mx;
  }
}

// Pass B1: one block per bucket — scan its 256 per-block counts.
__global__ void k_bprefix(const int* __restrict__ gcnt, int* __restrict__ ecur,
                          int* __restrict__ btot, int B){
  int b = blockIdx.x;
  int t = threadIdx.x;            // = source block id
  int v = gcnt[t * B + b];
  int lane = t & 63, wid = t >> 6;
  int x = v;
  #pragma unroll
  for (int off = 1; off < 64; off <<= 1){
    int tmp = __shfl_up(x, off, 64);
    if (lane >= off) x += tmp;
  }
  __shared__ int ws[4];
  if (lane == 63) ws[wid] = x;
  __syncthreads();
  if (t == 0){
    int s = 0;
    #pragma unroll
    for (int i = 0; i < 4; ++i){ int tmp = ws[i]; ws[i] = s; s += tmp; }
  }
  __syncthreads();
  int excl = ws[wid] + x - v;
  ecur[b * NB + t] = excl;
  if (t == 255) btot[b] = excl + v;
}

// Pass B2: single block — scan B bucket totals -> bstart; also reduce
// gblkmax -> asmaxf[4] and init h2mm (runs after gemm1, before agg1).
__global__ void k_btscan(const int* __restrict__ btot, int* __restrict__ bstart,
                         const float* __restrict__ gblkmax, float* __restrict__ asmaxf,
                         unsigned* __restrict__ h2mm, int B, int T){
  __shared__ int wsum[16];
  __shared__ int carry_s;
  __shared__ unsigned smenc[4];
  int lane = threadIdx.x & 63, wid = threadIdx.x >> 6;
  if (threadIdx.x == 0) carry_s = 0;
  if (threadIdx.x < 4) smenc[threadIdx.x] = 0u;
  __syncthreads();
  for (int base = 0; base < B; base += 1024){
    int i = base + (int)threadIdx.x;
    int v = (i < B) ? btot[i] : 0;
    int x = v;
    #pragma unroll
    for (int off = 1; off < 64; off <<= 1){
      int t = __shfl_up(x, off, 64);
      if (lane >= off) x += t;
    }
    if (lane == 63) wsum[wid] = x;
    __syncthreads();
    if (wid == 0 && lane < 16){
      int w = wsum[lane];
      #pragma unroll
      for (int off = 1; off < 16; off <<= 1){
        int t = __shfl_up(w, off, 64);
        if (lane >= off) w += t;
      }
      wsum[lane] = w;
    }
    __syncthreads();
    int carry = carry_s;
    int prefix = carry + (wid ? wsum[wid - 1] : 0);
    if (i < B) bstart[i] = prefix + x - v;
    __syncthreads();
    if (threadIdx.x == 1023) carry_s = carry + wsum[15];
    __syncthreads();
  }
  if (threadIdx.x == 0) bstart[B] = T;
  // reduce per-block head maxima (stride 1024 is %4==0 -> fixed head per thread)
  float lmax = -INFINITY;
  for (int i = threadIdx.x; i < B * 4; i += 1024) lmax = fmaxf(lmax, gblkmax[i]);
  atomicMax(&smenc[threadIdx.x & 3], fenc(lmax));
  __syncthreads();
  if (threadIdx.x < 4) asmaxf[threadIdx.x] = fdec(smenc[threadIdx.x]);
  if (threadIdx.x < 2) h2mm[threadIdx.x] = 0u;
}

// Pass C: scatter packed (dloc,src) into bucket-partitioned ebuf (4B/edge)
__global__ void k_bscatter(const int* __restrict__ ei, const int* __restrict__ ecur,
                           const int* __restrict__ bstart,
                           unsigned* __restrict__ ebuf,
                           int E, int N, int B, int chunk){
  __shared__ int cur[512];
  for (int t = threadIdx.x; t < B; t += 256)
    cur[t] = ecur[t * NB + blockIdx.x] + bstart[t];
  __syncthreads();
  int T = E + N;
  int lo = blockIdx.x * chunk;
  int hi = min(lo + chunk, T);
  for (int i = lo + (int)threadIdx.x; i < hi; i += 256){
    int s, d;
    if (i < E){ s = ei[i]; d = ei[E + i]; } else { s = d = i - E; }
    int pos = atomicAdd(&cur[d >> BSHIFT], 1);
    ebuf[pos] = ((unsigned)(d & 127) << 25) | (unsigned)s;
  }
}

// Pass D: one block per bucket; LDS 128-dst hist + scan -> rs + final csr
__global__ void k_bfinal(const unsigned* __restrict__ ebuf,
                         const int* __restrict__ bstart,
                         int* __restrict__ csr, int* __restrict__ rs,
                         int N, int B, int T){
  int b = blockIdx.x;
  int d0 = b << BSHIFT;
  int dcount = min(128, N - d0);
  int ebeg = bstart[b];
  int eend = bstart[b + 1];
  __shared__ int hist[128];
  __shared__ int excl[128];
  if (threadIdx.x < 128) hist[threadIdx.x] = 0;
  __syncthreads();
  for (int i = ebeg + (int)threadIdx.x; i < eend; i += 256)
    atomicAdd(&hist[ebuf[i] >> 25], 1);
  __syncthreads();
  if (threadIdx.x < 64){
    int l = threadIdx.x;
    int v0 = hist[l], v1 = hist[l + 64];
    int s0 = v0, s1 = v1;
    #pragma unroll
    for (int off = 1; off < 64; off <<= 1){
      int t0 = __shfl_up(s0, off, 64); if (l >= off) s0 += t0;
      int t1 = __shfl_up(s1, off, 64); if (l >= off) s1 += t1;
    }
    int tot0 = __shfl(s0, 63, 64);
    excl[l] = s0 - v0;
    excl[l + 64] = tot0 + s1 - v1;
  }
  __syncthreads();
  if (threadIdx.x < dcount) rs[d0 + threadIdx.x] = ebeg + excl[threadIdx.x];
  if (threadIdx.x < 128) hist[threadIdx.x] = excl[threadIdx.x];  // -> cursor
  if (b == 0 && threadIdx.x == 255) rs[N] = T;
  __syncthreads();
  for (int i = ebeg + (int)threadIdx.x; i < eend; i += 256){
    unsigned e = ebuf[i];
    int pos = ebeg + atomicAdd(&hist[e >> 25], 1);
    csr[pos] = (int)(e & 0x01FFFFFFu);
  }
}

// ---- Layer 1 aggregation: one wave per dst, 16 lanes per edge (8 fp16 ch/lane),
// 8 edges in flight (2 chains of 4) — the measured-fast round-8 structure.
// Softmax via global upper bound. Fuses /den, +bias, ELU, dot W2 -> h2[d]
// + per-block h2 min/max atomics (valid-flag pattern keeps barriers safe).
__global__ void k_agg1(const int* __restrict__ csr, const int* __restrict__ rs,
                       const float* __restrict__ as1, const float* __restrict__ ad1,
                       const float* __restrict__ asmaxf,
                       const float4* __restrict__ h1,
                       const float* __restrict__ bias1,
                       const float* __restrict__ W2, float* __restrict__ h2,
                       unsigned* __restrict__ h2mm, int N){
  __shared__ float hmax4[4], hmin4[4];
  int wv = threadIdx.x >> 6;
  int lane = threadIdx.x & 63;
  int d = blockIdx.x * 4 + wv;
  bool valid = d < N;
  int g = lane >> 4;          // edge subgroup 0..3
  int m = lane & 15;          // channels 8m..8m+7
  int h = m >> 2;             // head
  float adh = valid ? ad1[d * 4 + h] : 0.f;
  float M = lrelu(asmaxf[h] + adh);
  int beg = 0, end = 0;
  if (valid){ beg = rs[d]; end = rs[d + 1]; }
  float den = 0.f;
  float a0=0.f,a1=0.f,a2=0.f,a3=0.f,a4=0.f,a5=0.f,a6=0.f,a7=0.f;
  int j = beg;
  for (; j + 8 <= end; j += 8){
    int sA = csr[j + g];
    int sB = csr[j + 4 + g];
    float eA = lrelu(as1[sA * 4 + h] + adh);
    float eB = lrelu(as1[sB * 4 + h] + adh);
    float pA = __expf(eA - M);
    float pB = __expf(eB - M);
    float4 rA = h1[(size_t)sA * 16 + m];
    float4 rB = h1[(size_t)sB * 16 + m];
    den += pA + pB;
    float2 cA0 = __half22float2(*(__half2*)&rA.x);
    float2 cA1 = __half22float2(*(__half2*)&rA.y);
    float2 cA2 = __half22float2(*(__half2*)&rA.z);
    float2 cA3 = __half22float2(*(__half2*)&rA.w);
    a0 = fmaf(pA, cA0.x, a0); a1 = fmaf(pA, cA0.y, a1);
    a2 = fmaf(pA, cA1.x, a2); a3 = fmaf(pA, cA1.y, a3);
    a4 = fmaf(pA, cA2.x, a4); a5 = fmaf(pA, cA2.y, a5);
    a6 = fmaf(pA, cA3.x, a6); a7 = fmaf(pA, cA3.y, a7);
    float2 cB0 = __half22float2(*(__half2*)&rB.x);
    float2 cB1 = __half22float2(*(__half2*)&rB.y);
    float2 cB2 = __half22float2(*(__half2*)&rB.z);
    float2 cB3 = __half22float2(*(__half2*)&rB.w);
    a0 = fmaf(pB, cB0.x, a0); a1 = fmaf(pB, cB0.y, a1);
    a2 = fmaf(pB, cB1.x, a2); a3 = fmaf(pB, cB1.y, a3);
    a4 = fmaf(pB, cB2.x, a4); a5 = fmaf(pB, cB2.y, a5);
    a6 = fmaf(pB, cB3.x, a6); a7 = fmaf(pB, cB3.y, a7);
  }
  for (; j < end; j += 4){
    int slot = j + g;
    bool v = slot < end;
    int s = csr[v ? slot : beg];
    float e = lrelu(as1[s * 4 + h] + adh);
    float p = v ? __expf(e - M) : 0.f;
    float4 raw = h1[(size_t)s * 16 + m];
    float2 c0 = __half22float2(*(__half2*)&raw.x);
    float2 c1 = __half22float2(*(__half2*)&raw.y);
    float2 c2 = __half22float2(*(__half2*)&raw.z);
    float2 c3 = __half22float2(*(__half2*)&raw.w);
    den += p;
    a0 = fmaf(p, c0.x, a0); a1 = fmaf(p, c0.y, a1);
    a2 = fmaf(p, c1.x, a2); a3 = fmaf(p, c1.y, a3);
    a4 = fmaf(p, c2.x, a4); a5 = fmaf(p, c2.y, a5);
    a6 = fmaf(p, c3.x, a6); a7 = fmaf(p, c3.y, a7);
  }
  #define CMB(v) v += __shfl_xor(v, 16); v += __shfl_xor(v, 32);
  CMB(a0) CMB(a1) CMB(a2) CMB(a3) CMB(a4) CMB(a5) CMB(a6) CMB(a7) CMB(den)
  #undef CMB
  float part = 0.f;
  if (lane < 16){
    float invden = 1.f / den;
    float4 b03 = ((const float4*)bias1)[2 * m];
    float4 b47 = ((const float4*)bias1)[2 * m + 1];
    float4 w03 = ((const float4*)W2)[2 * m];
    float4 w47 = ((const float4*)W2)[2 * m + 1];
    part  = elu1(a0 * invden + b03.x) * w03.x;
    part += elu1(a1 * invden + b03.y) * w03.y;
    part += elu1(a2 * invden + b03.z) * w03.z;
    part += elu1(a3 * invden + b03.w) * w03.w;
    part += elu1(a4 * invden + b47.x) * w47.x;
    part += elu1(a5 * invden + b47.y) * w47.y;
    part += elu1(a6 * invden + b47.z) * w47.z;
    part += elu1(a7 * invden + b47.w) * w47.w;
  }
  #pragma unroll
  for (int off = 8; off; off >>= 1) part += __shfl_down(part, off);
  if (lane == 0){
    if (valid) h2[d] = part;
    hmax4[wv] = valid ? part : -INFINITY;
    hmin4[wv] = valid ? part : INFINITY;
  }
  __syncthreads();
  if (threadIdx.x == 0){
    float mx = fmaxf(fmaxf(hmax4[0], hmax4[1]), fmaxf(hmax4[2], hmax4[3]));
    float mn = fminf(fminf(hmin4[0], hmin4[1]), fminf(hmin4[2], hmin4[3]));
    atomicMax(&h2mm[0], fenc(mx));
    atomicMax(&h2mm[1], fenc(-mn));
  }
}

// Layer 2: 16 lanes per dst (4 dsts/wave), single pass (bound-stabilized).
__global__ void k_agg2(const int* __restrict__ csr, const int* __restrict__ rs,
                       const float* __restrict__ h2, const unsigned* __restrict__ h2mm,
                       const float* __restrict__ as2p, const float* __restrict__ ad2p,
                       const float* __restrict__ bias2, float* __restrict__ out, int N){
  int grp = threadIdx.x >> 4;     // 16 groups per block
  int l16 = threadIdx.x & 15;
  int d = blockIdx.x * 16 + grp;
  if (d >= N) return;
  float asc = as2p[0];
  float hmax = fdec(h2mm[0]), hmn = -fdec(h2mm[1]);
  float bound = (asc >= 0.f) ? asc * hmax : asc * hmn;
  float hd = h2[d] * ad2p[0];
  float M = lrelu(bound + hd);
  int beg = rs[d], end = rs[d + 1];
  float den = 0.f, acc = 0.f;
  for (int j = beg + l16; j < end; j += 16){
    float hs = h2[csr[j]];
    float p = __expf(lrelu(hs * asc + hd) - M);
    den += p;
    acc = fmaf(p, hs, acc);
  }
  #pragma unroll
  for (int off = 8; off; off >>= 1){
    den += __shfl_xor(den, off, 16);
    acc += __shfl_xor(acc, off, 16);
  }
  if (l16 == 0) out[d] = acc / den + bias2[0];
}

extern "C" void kernel_launch(void* const* d_in, const int* in_sizes, int n_in,
                              void* d_out, int out_size, void* d_ws, size_t ws_size,
                              hipStream_t stream){
  const float* x     = (const float*)d_in[0];
  const int*   ei    = (const int*)  d_in[1];
  const float* W1    = (const float*)d_in[2];
  const float* atts1 = (const float*)d_in[3];
  const float* attd1 = (const float*)d_in[4];
  const float* bias1 = (const float*)d_in[5];
  const float* W2    = (const float*)d_in[6];
  const float* atts2 = (const float*)d_in[7];
  const float* attd2 = (const float*)d_in[8];
  const float* bias2 = (const float*)d_in[9];

  int N = in_sizes[0] / 128;   // D = 128
  int E = in_sizes[1] / 2;
  int T = E + N;
  int B = (N + 127) >> BSHIFT;           // dst buckets of 128
  int chunk = (T + NB - 1) / NB;
  int G = (N + 127) / 128;               // gemm blocks

  // workspace layout — EVERY sub-buffer 256-byte aligned (h1 is float4-accessed).
  uintptr_t base = (uintptr_t)d_ws;
  auto take = [&](size_t bytes) -> uintptr_t {
    base = (base + 255) & ~(uintptr_t)255;
    uintptr_t r = base;
    base += bytes;
    return r;
  };
  __half* h1     = (__half*)  take((size_t)N * 128 * 2);
  unsigned* ebuf = (unsigned*)take((size_t)T * 4);
  float*  as1    = (float*)   take((size_t)N * 4 * 4);
  float*  ad1    = (float*)   take((size_t)N * 4 * 4);
  float*  h2     = (float*)   take((size_t)N * 4);
  int*    gcnt   = (int*)     take((size_t)NB * B * 4);
  int*    ecur   = (int*)     take((size_t)NB * B * 4);
  int*    csr    = (int*)     take((size_t)T * 4);
  int*    rs     = (int*)     take((size_t)(N + 1) * 4);
  int*    btot   = (int*)     take((size_t)B * 4);
  int*    bstart = (int*)     take((size_t)(B + 1) * 4);
  float*  gblkmax= (float*)   take((size_t)G * 4 * 4);
  float*  asmaxf = (float*)   take(4 * 4);
  unsigned* h2mm = (unsigned*)take(2 * 4);

  k_gemm1_hist<<<G + NB, 256, 0, stream>>>(x, W1, atts1, attd1, h1, as1, ad1,
                                           gblkmax, ei, gcnt, E, N, B, chunk, G);
  k_bprefix <<<B, 256, 0, stream>>>(gcnt, ecur, btot, B);
  k_btscan  <<<1, 1024, 0, stream>>>(btot, bstart, gblkmax, asmaxf, h2mm, B, T);
  k_bscatter<<<NB, 256, 0, stream>>>(ei, ecur, bstart, ebuf, E, N, B, chunk);
  k_bfinal  <<<B, 256, 0, stream>>>(ebuf, bstart, csr, rs, N, B, T);
  k_agg1    <<<(N + 3) / 4, 256, 0, stream>>>(csr, rs, as1, ad1, asmaxf,
                                              (const float4*)h1, bias1, W2, h2, h2mm, N);
  k_agg2    <<<(N + 15) / 16, 256, 0, stream>>>(csr, rs, h2, h2mm, atts2, attd2,
                                                bias2, (float*)d_out, N);
}

// Round 14
// 162.954 us; speedup vs baseline: 2.4628x; 2.4628x over previous
//
#include <hip/hip_runtime.h>
#include <hip/hip_fp16.h>
#include <stdint.h>

#define NEG_SLOPE 0.2f
#define BSHIFT 7          // bucket = dst >> 7  (128 dsts per bucket)
#define NB 256            // blocks in bucket hist/scatter passes

__device__ __forceinline__ float lrelu(float x){ return x > 0.f ? x : NEG_SLOPE * x; }
__device__ __forceinline__ float elu1(float x){ return x > 0.f ? x : expm1f(x); }
// float -> ordered uint encoding for atomicMax over signed floats
__device__ __forceinline__ unsigned fenc(float f){
  unsigned u = __float_as_uint(f);
  return (u & 0x80000000u) ? ~u : (u | 0x80000000u);
}
__device__ __forceinline__ float fdec(unsigned u){
  return (u & 0x80000000u) ? __uint_as_float(u & 0x7fffffffu) : __uint_as_float(~u);
}

// Fused: blocks [0,G) = h1 GEMM (128x128 tile, 8x8 reg tile);
//        blocks [G,G+NB) = per-block dst-bucket histogram (independent inputs).
__global__ __launch_bounds__(256) void k_gemm1_hist(
    const float* __restrict__ x, const float* __restrict__ W1,
    const float* __restrict__ atts, const float* __restrict__ attd,
    __half* __restrict__ h1, float* __restrict__ as1, float* __restrict__ ad1,
    float* __restrict__ gblkmax,
    const int* __restrict__ ei, int* __restrict__ gcnt,
    int E, int N, int B, int chunk, int G){
  __shared__ float xs[128 * 128];   // 64 KB exactly (hist part reuses prefix)
  if (blockIdx.x >= G){
    // ---- histogram part ----
    int bid = blockIdx.x - G;
    int* hist = (int*)xs;           // first 512 ints
    for (int t = threadIdx.x; t < B; t += 256) hist[t] = 0;
    __syncthreads();
    int T = E + N;
    int lo = bid * chunk;
    int hi = min(lo + chunk, T);
    for (int i = lo + (int)threadIdx.x; i < hi; i += 256){
      int d = (i < E) ? ei[E + i] : (i - E);
      atomicAdd(&hist[d >> BSHIFT], 1);
    }
    __syncthreads();
    for (int t = threadIdx.x; t < B; t += 256) gcnt[bid * B + t] = hist[t];
    return;
  }
  // ---- GEMM part ----
  int n0 = blockIdx.x * 128;
  int t = threadIdx.x;
  {
    int row = t & 127;
    int kc = t >> 7;                // 0 or 1 (k-half)
    int n = n0 + row;
    const float4* x4 = (const float4*)x;
    #pragma unroll 4
    for (int i = 0; i < 16; ++i){
      float4 v = (n < N) ? x4[(size_t)n * 32 + kc * 16 + i]
                         : make_float4(0.f, 0.f, 0.f, 0.f);
      int k = kc * 64 + 4 * i;
      xs[(k + 0) * 128 + row] = v.x;
      xs[(k + 1) * 128 + row] = v.y;
      xs[(k + 2) * 128 + row] = v.z;
      xs[(k + 3) * 128 + row] = v.w;
    }
  }
  __syncthreads();
  int m = t & 15;                 // cols 8m..8m+7
  int rg = t >> 4;                // rows 8rg..8rg+7
  int rb = rg * 8;
  const float4* W14 = (const float4*)W1;
  float acc[8][8];
  #pragma unroll
  for (int r = 0; r < 8; ++r)
    #pragma unroll
    for (int c = 0; c < 8; ++c) acc[r][c] = 0.f;
  #pragma unroll 2
  for (int k = 0; k < 128; ++k){
    float4 w0 = W14[k * 32 + 2 * m];
    float4 w1 = W14[k * 32 + 2 * m + 1];
    float4 xa = *(const float4*)&xs[k * 128 + rb];
    float4 xb = *(const float4*)&xs[k * 128 + rb + 4];
    float xr[8] = {xa.x, xa.y, xa.z, xa.w, xb.x, xb.y, xb.z, xb.w};
    float wc[8] = {w0.x, w0.y, w0.z, w0.w, w1.x, w1.y, w1.z, w1.w};
    #pragma unroll
    for (int r = 0; r < 8; ++r)
      #pragma unroll
      for (int c = 0; c < 8; ++c)
        acc[r][c] = fmaf(xr[r], wc[c], acc[r][c]);
  }
  float4 av0 = ((const float4*)atts)[2 * m], av1 = ((const float4*)atts)[2 * m + 1];
  float4 dv0 = ((const float4*)attd)[2 * m], dv1 = ((const float4*)attd)[2 * m + 1];
  int h = m >> 2;                 // head of cols 8m..8m+7
  float lmax = -INFINITY;
  #pragma unroll
  for (int r = 0; r < 8; ++r){
    int n = n0 + rb + r;
    if (n < N){
      union { __half2 hh[4]; float4 f; } u;
      u.hh[0] = __floats2half2_rn(acc[r][0], acc[r][1]);
      u.hh[1] = __floats2half2_rn(acc[r][2], acc[r][3]);
      u.hh[2] = __floats2half2_rn(acc[r][4], acc[r][5]);
      u.hh[3] = __floats2half2_rn(acc[r][6], acc[r][7]);
      *(float4*)(h1 + (size_t)n * 128 + 8 * m) = u.f;
    }
    float s  = acc[r][0]*av0.x + acc[r][1]*av0.y + acc[r][2]*av0.z + acc[r][3]*av0.w
             + acc[r][4]*av1.x + acc[r][5]*av1.y + acc[r][6]*av1.z + acc[r][7]*av1.w;
    float dd = acc[r][0]*dv0.x + acc[r][1]*dv0.y + acc[r][2]*dv0.z + acc[r][3]*dv0.w
             + acc[r][4]*dv1.x + acc[r][5]*dv1.y + acc[r][6]*dv1.z + acc[r][7]*dv1.w;
    s  += __shfl_down(s, 1);  s  += __shfl_down(s, 2);
    dd += __shfl_down(dd, 1); dd += __shfl_down(dd, 2);
    lmax = fmaxf(lmax, s);
    if ((m & 3) == 0 && n < N){
      as1[n * 4 + h] = s;
      ad1[n * 4 + h] = dd;
    }
  }
  // per-block head max -> gblkmax[blk*4+h]  (reuse xs after all reads done)
  __syncthreads();
  if ((m & 3) == 0) xs[(m >> 2) * 16 + rg] = lmax;
  __syncthreads();
  if (t < 4){
    float mx = xs[t * 16];
    #pragma unroll
    for (int i = 1; i < 16; ++i) mx = fmaxf(mx, xs[t * 16 + i]);
    gblkmax[blockIdx.x * 4 + t] = mx;
  }
}

// Pass B1: one block per bucket — scan its 256 per-block counts.
__global__ void k_bprefix(const int* __restrict__ gcnt, int* __restrict__ ecur,
                          int* __restrict__ btot, int B){
  int b = blockIdx.x;
  int t = threadIdx.x;            // = source block id
  int v = gcnt[t * B + b];
  int lane = t & 63, wid = t >> 6;
  int x = v;
  #pragma unroll
  for (int off = 1; off < 64; off <<= 1){
    int tmp = __shfl_up(x, off, 64);
    if (lane >= off) x += tmp;
  }
  __shared__ int ws[4];
  if (lane == 63) ws[wid] = x;
  __syncthreads();
  if (t == 0){
    int s = 0;
    #pragma unroll
    for (int i = 0; i < 4; ++i){ int tmp = ws[i]; ws[i] = s; s += tmp; }
  }
  __syncthreads();
  int excl = ws[wid] + x - v;
  ecur[b * NB + t] = excl;
  if (t == 255) btot[b] = excl + v;
}

// Pass B2: single block — scan B bucket totals -> bstart; also reduce
// gblkmax -> asmaxf[4] and init h2mm (runs after gemm1, before agg1).
__global__ void k_btscan(const int* __restrict__ btot, int* __restrict__ bstart,
                         const float* __restrict__ gblkmax, float* __restrict__ asmaxf,
                         unsigned* __restrict__ h2mm, int B, int T){
  __shared__ int wsum[16];
  __shared__ int carry_s;
  __shared__ unsigned smenc[4];
  int lane = threadIdx.x & 63, wid = threadIdx.x >> 6;
  if (threadIdx.x == 0) carry_s = 0;
  if (threadIdx.x < 4) smenc[threadIdx.x] = 0u;
  __syncthreads();
  for (int base = 0; base < B; base += 1024){
    int i = base + (int)threadIdx.x;
    int v = (i < B) ? btot[i] : 0;
    int x = v;
    #pragma unroll
    for (int off = 1; off < 64; off <<= 1){
      int t = __shfl_up(x, off, 64);
      if (lane >= off) x += t;
    }
    if (lane == 63) wsum[wid] = x;
    __syncthreads();
    if (wid == 0 && lane < 16){
      int w = wsum[lane];
      #pragma unroll
      for (int off = 1; off < 16; off <<= 1){
        int t = __shfl_up(w, off, 64);
        if (lane >= off) w += t;
      }
      wsum[lane] = w;
    }
    __syncthreads();
    int carry = carry_s;
    int prefix = carry + (wid ? wsum[wid - 1] : 0);
    if (i < B) bstart[i] = prefix + x - v;
    __syncthreads();
    if (threadIdx.x == 1023) carry_s = carry + wsum[15];
    __syncthreads();
  }
  if (threadIdx.x == 0) bstart[B] = T;
  // reduce per-block head maxima (stride 1024 is %4==0 -> fixed head per thread)
  float lmax = -INFINITY;
  for (int i = threadIdx.x; i < B * 4; i += 1024) lmax = fmaxf(lmax, gblkmax[i]);
  atomicMax(&smenc[threadIdx.x & 3], fenc(lmax));
  __syncthreads();
  if (threadIdx.x < 4) asmaxf[threadIdx.x] = fdec(smenc[threadIdx.x]);
  if (threadIdx.x < 2) h2mm[threadIdx.x] = 0u;
}

// Pass C: scatter packed (dloc,src) into bucket-partitioned ebuf (4B/edge)
__global__ void k_bscatter(const int* __restrict__ ei, const int* __restrict__ ecur,
                           const int* __restrict__ bstart,
                           unsigned* __restrict__ ebuf,
                           int E, int N, int B, int chunk){
  __shared__ int cur[512];
  for (int t = threadIdx.x; t < B; t += 256)
    cur[t] = ecur[t * NB + blockIdx.x] + bstart[t];
  __syncthreads();
  int T = E + N;
  int lo = blockIdx.x * chunk;
  int hi = min(lo + chunk, T);
  for (int i = lo + (int)threadIdx.x; i < hi; i += 256){
    int s, d;
    if (i < E){ s = ei[i]; d = ei[E + i]; } else { s = d = i - E; }
    int pos = atomicAdd(&cur[d >> BSHIFT], 1);
    ebuf[pos] = ((unsigned)(d & 127) << 25) | (unsigned)s;
  }
}

// Pass D: one block per bucket; LDS 128-dst hist + scan -> rs + final csr
__global__ void k_bfinal(const unsigned* __restrict__ ebuf,
                         const int* __restrict__ bstart,
                         int* __restrict__ csr, int* __restrict__ rs,
                         int N, int B, int T){
  int b = blockIdx.x;
  int d0 = b << BSHIFT;
  int dcount = min(128, N - d0);
  int ebeg = bstart[b];
  int eend = bstart[b + 1];
  __shared__ int hist[128];
  __shared__ int excl[128];
  if (threadIdx.x < 128) hist[threadIdx.x] = 0;
  __syncthreads();
  for (int i = ebeg + (int)threadIdx.x; i < eend; i += 256)
    atomicAdd(&hist[ebuf[i] >> 25], 1);
  __syncthreads();
  if (threadIdx.x < 64){
    int l = threadIdx.x;
    int v0 = hist[l], v1 = hist[l + 64];
    int s0 = v0, s1 = v1;
    #pragma unroll
    for (int off = 1; off < 64; off <<= 1){
      int t0 = __shfl_up(s0, off, 64); if (l >= off) s0 += t0;
      int t1 = __shfl_up(s1, off, 64); if (l >= off) s1 += t1;
    }
    int tot0 = __shfl(s0, 63, 64);
    excl[l] = s0 - v0;
    excl[l + 64] = tot0 + s1 - v1;
  }
  __syncthreads();
  if (threadIdx.x < dcount) rs[d0 + threadIdx.x] = ebeg + excl[threadIdx.x];
  if (threadIdx.x < 128) hist[threadIdx.x] = excl[threadIdx.x];  // -> cursor
  if (b == 0 && threadIdx.x == 255) rs[N] = T;
  __syncthreads();
  for (int i = ebeg + (int)threadIdx.x; i < eend; i += 256){
    unsigned e = ebuf[i];
    int pos = ebeg + atomicAdd(&hist[e >> 25], 1);
    csr[pos] = (int)(e & 0x01FFFFFFu);
  }
}

// ---- Layer 1 aggregation: one wave per dst, 16 lanes per edge (8 fp16 ch/lane),
// 8 edges in flight (2 chains of 4) — the measured-fast round-8/12 structure.
// Softmax via global upper bound. Fuses /den, +bias, ELU, dot W2 -> h2[d].
// NO h2mm fusion: contended cross-XCD atomics per block cost ~240 us (b9-b13).
__global__ void k_agg1(const int* __restrict__ csr, const int* __restrict__ rs,
                       const float* __restrict__ as1, const float* __restrict__ ad1,
                       const float* __restrict__ asmaxf,
                       const float4* __restrict__ h1,
                       const float* __restrict__ bias1,
                       const float* __restrict__ W2, float* __restrict__ h2, int N){
  int wv = threadIdx.x >> 6;
  int lane = threadIdx.x & 63;
  int d = blockIdx.x * 4 + wv;
  if (d >= N) return;
  int g = lane >> 4;          // edge subgroup 0..3
  int m = lane & 15;          // channels 8m..8m+7
  int h = m >> 2;             // head
  float adh = ad1[d * 4 + h];
  float M = lrelu(asmaxf[h] + adh);
  int beg = rs[d], end = rs[d + 1];
  float den = 0.f;
  float a0=0.f,a1=0.f,a2=0.f,a3=0.f,a4=0.f,a5=0.f,a6=0.f,a7=0.f;
  int j = beg;
  for (; j + 8 <= end; j += 8){
    int sA = csr[j + g];
    int sB = csr[j + 4 + g];
    float eA = lrelu(as1[sA * 4 + h] + adh);
    float eB = lrelu(as1[sB * 4 + h] + adh);
    float pA = __expf(eA - M);
    float pB = __expf(eB - M);
    float4 rA = h1[(size_t)sA * 16 + m];
    float4 rB = h1[(size_t)sB * 16 + m];
    den += pA + pB;
    float2 cA0 = __half22float2(*(__half2*)&rA.x);
    float2 cA1 = __half22float2(*(__half2*)&rA.y);
    float2 cA2 = __half22float2(*(__half2*)&rA.z);
    float2 cA3 = __half22float2(*(__half2*)&rA.w);
    a0 = fmaf(pA, cA0.x, a0); a1 = fmaf(pA, cA0.y, a1);
    a2 = fmaf(pA, cA1.x, a2); a3 = fmaf(pA, cA1.y, a3);
    a4 = fmaf(pA, cA2.x, a4); a5 = fmaf(pA, cA2.y, a5);
    a6 = fmaf(pA, cA3.x, a6); a7 = fmaf(pA, cA3.y, a7);
    float2 cB0 = __half22float2(*(__half2*)&rB.x);
    float2 cB1 = __half22float2(*(__half2*)&rB.y);
    float2 cB2 = __half22float2(*(__half2*)&rB.z);
    float2 cB3 = __half22float2(*(__half2*)&rB.w);
    a0 = fmaf(pB, cB0.x, a0); a1 = fmaf(pB, cB0.y, a1);
    a2 = fmaf(pB, cB1.x, a2); a3 = fmaf(pB, cB1.y, a3);
    a4 = fmaf(pB, cB2.x, a4); a5 = fmaf(pB, cB2.y, a5);
    a6 = fmaf(pB, cB3.x, a6); a7 = fmaf(pB, cB3.y, a7);
  }
  for (; j < end; j += 4){
    int slot = j + g;
    bool v = slot < end;
    int s = csr[v ? slot : beg];
    float e = lrelu(as1[s * 4 + h] + adh);
    float p = v ? __expf(e - M) : 0.f;
    float4 raw = h1[(size_t)s * 16 + m];
    float2 c0 = __half22float2(*(__half2*)&raw.x);
    float2 c1 = __half22float2(*(__half2*)&raw.y);
    float2 c2 = __half22float2(*(__half2*)&raw.z);
    float2 c3 = __half22float2(*(__half2*)&raw.w);
    den += p;
    a0 = fmaf(p, c0.x, a0); a1 = fmaf(p, c0.y, a1);
    a2 = fmaf(p, c1.x, a2); a3 = fmaf(p, c1.y, a3);
    a4 = fmaf(p, c2.x, a4); a5 = fmaf(p, c2.y, a5);
    a6 = fmaf(p, c3.x, a6); a7 = fmaf(p, c3.y, a7);
  }
  #define CMB(v) v += __shfl_xor(v, 16); v += __shfl_xor(v, 32);
  CMB(a0) CMB(a1) CMB(a2) CMB(a3) CMB(a4) CMB(a5) CMB(a6) CMB(a7) CMB(den)
  #undef CMB
  float part = 0.f;
  if (lane < 16){
    float invden = 1.f / den;
    float4 b03 = ((const float4*)bias1)[2 * m];
    float4 b47 = ((const float4*)bias1)[2 * m + 1];
    float4 w03 = ((const float4*)W2)[2 * m];
    float4 w47 = ((const float4*)W2)[2 * m + 1];
    part  = elu1(a0 * invden + b03.x) * w03.x;
    part += elu1(a1 * invden + b03.y) * w03.y;
    part += elu1(a2 * invden + b03.z) * w03.z;
    part += elu1(a3 * invden + b03.w) * w03.w;
    part += elu1(a4 * invden + b47.x) * w47.x;
    part += elu1(a5 * invden + b47.y) * w47.y;
    part += elu1(a6 * invden + b47.z) * w47.z;
    part += elu1(a7 * invden + b47.w) * w47.w;
  }
  #pragma unroll
  for (int off = 8; off; off >>= 1) part += __shfl_down(part, off);
  if (lane == 0) h2[d] = part;
}

// global min/max of h2 (upper bound inputs for layer-2 softmax); few atomics.
__global__ void k_h2mm(const float* __restrict__ h2, unsigned* __restrict__ h2mm, int N){
  float mx = -INFINITY, mn = INFINITY;
  for (int i = blockIdx.x * blockDim.x + threadIdx.x; i < N; i += gridDim.x * blockDim.x){
    float v = h2[i];
    mx = fmaxf(mx, v); mn = fminf(mn, v);
  }
  #pragma unroll
  for (int off = 1; off < 64; off <<= 1){
    mx = fmaxf(mx, __shfl_xor(mx, off));
    mn = fminf(mn, __shfl_xor(mn, off));
  }
  if ((threadIdx.x & 63) == 0){
    atomicMax(&h2mm[0], fenc(mx));
    atomicMax(&h2mm[1], fenc(-mn));
  }
}

// Layer 2: 16 lanes per dst (4 dsts/wave), single pass (bound-stabilized).
__global__ void k_agg2(const int* __restrict__ csr, const int* __restrict__ rs,
                       const float* __restrict__ h2, const unsigned* __restrict__ h2mm,
                       const float* __restrict__ as2p, const float* __restrict__ ad2p,
                       const float* __restrict__ bias2, float* __restrict__ out, int N){
  int grp = threadIdx.x >> 4;     // 16 groups per block
  int l16 = threadIdx.x & 15;
  int d = blockIdx.x * 16 + grp;
  if (d >= N) return;
  float asc = as2p[0];
  float hmax = fdec(h2mm[0]), hmn = -fdec(h2mm[1]);
  float bound = (asc >= 0.f) ? asc * hmax : asc * hmn;
  float hd = h2[d] * ad2p[0];
  float M = lrelu(bound + hd);
  int beg = rs[d], end = rs[d + 1];
  float den = 0.f, acc = 0.f;
  for (int j = beg + l16; j < end; j += 16){
    float hs = h2[csr[j]];
    float p = __expf(lrelu(hs * asc + hd) - M);
    den += p;
    acc = fmaf(p, hs, acc);
  }
  #pragma unroll
  for (int off = 8; off; off >>= 1){
    den += __shfl_xor(den, off, 16);
    acc += __shfl_xor(acc, off, 16);
  }
  if (l16 == 0) out[d] = acc / den + bias2[0];
}

extern "C" void kernel_launch(void* const* d_in, const int* in_sizes, int n_in,
                              void* d_out, int out_size, void* d_ws, size_t ws_size,
                              hipStream_t stream){
  const float* x     = (const float*)d_in[0];
  const int*   ei    = (const int*)  d_in[1];
  const float* W1    = (const float*)d_in[2];
  const float* atts1 = (const float*)d_in[3];
  const float* attd1 = (const float*)d_in[4];
  const float* bias1 = (const float*)d_in[5];
  const float* W2    = (const float*)d_in[6];
  const float* atts2 = (const float*)d_in[7];
  const float* attd2 = (const float*)d_in[8];
  const float* bias2 = (const float*)d_in[9];

  int N = in_sizes[0] / 128;   // D = 128
  int E = in_sizes[1] / 2;
  int T = E + N;
  int B = (N + 127) >> BSHIFT;           // dst buckets of 128
  int chunk = (T + NB - 1) / NB;
  int G = (N + 127) / 128;               // gemm blocks

  // workspace layout — EVERY sub-buffer 256-byte aligned (h1 is float4-accessed).
  uintptr_t base = (uintptr_t)d_ws;
  auto take = [&](size_t bytes) -> uintptr_t {
    base = (base + 255) & ~(uintptr_t)255;
    uintptr_t r = base;
    base += bytes;
    return r;
  };
  __half* h1     = (__half*)  take((size_t)N * 128 * 2);
  unsigned* ebuf = (unsigned*)take((size_t)T * 4);
  float*  as1    = (float*)   take((size_t)N * 4 * 4);
  float*  ad1    = (float*)   take((size_t)N * 4 * 4);
  float*  h2     = (float*)   take((size_t)N * 4);
  int*    gcnt   = (int*)     take((size_t)NB * B * 4);
  int*    ecur   = (int*)     take((size_t)NB * B * 4);
  int*    csr    = (int*)     take((size_t)T * 4);
  int*    rs     = (int*)     take((size_t)(N + 1) * 4);
  int*    btot   = (int*)     take((size_t)B * 4);
  int*    bstart = (int*)     take((size_t)(B + 1) * 4);
  float*  gblkmax= (float*)   take((size_t)G * 4 * 4);
  float*  asmaxf = (float*)   take(4 * 4);
  unsigned* h2mm = (unsigned*)take(2 * 4);

  k_gemm1_hist<<<G + NB, 256, 0, stream>>>(x, W1, atts1, attd1, h1, as1, ad1,
                                           gblkmax, ei, gcnt, E, N, B, chunk, G);
  k_bprefix <<<B, 256, 0, stream>>>(gcnt, ecur, btot, B);
  k_btscan  <<<1, 1024, 0, stream>>>(btot, bstart, gblkmax, asmaxf, h2mm, B, T);
  k_bscatter<<<NB, 256, 0, stream>>>(ei, ecur, bstart, ebuf, E, N, B, chunk);
  k_bfinal  <<<B, 256, 0, stream>>>(ebuf, bstart, csr, rs, N, B, T);
  k_agg1    <<<(N + 3) / 4, 256, 0, stream>>>(csr, rs, as1, ad1, asmaxf,
                                              (const float4*)h1, bias1, W2, h2, N);
  k_h2mm    <<<64, 256, 0, stream>>>(h2, h2mm, N);
  k_agg2    <<<(N + 15) / 16, 256, 0, stream>>>(csr, rs, h2, h2mm, atts2, attd2,
                                                bias2, (float*)d_out, N);
}

// Round 15
// 148.088 us; speedup vs baseline: 2.7100x; 1.1004x over previous
//
#include <hip/hip_runtime.h>
#include <hip/hip_fp16.h>
#include <stdint.h>

#define NEG_SLOPE 0.2f
#define BSHIFT 7          // bucket = dst >> 7  (128 dsts per bucket)
#define NB 256            // blocks in bucket hist/scatter passes

__device__ __forceinline__ float lrelu(float x){ return x > 0.f ? x : NEG_SLOPE * x; }
__device__ __forceinline__ float elu1(float x){ return x > 0.f ? x : expm1f(x); }
// float -> ordered uint encoding for atomicMax over signed floats
__device__ __forceinline__ unsigned fenc(float f){
  unsigned u = __float_as_uint(f);
  return (u & 0x80000000u) ? ~u : (u | 0x80000000u);
}
__device__ __forceinline__ float fdec(unsigned u){
  return (u & 0x80000000u) ? __uint_as_float(u & 0x7fffffffu) : __uint_as_float(~u);
}

// Fused: blocks [0,G) = h1 GEMM (128x128 tile, 8x8 reg tile);
//        blocks [G,G+NB) = per-block dst-bucket histogram (independent inputs).
__global__ __launch_bounds__(256) void k_gemm1_hist(
    const float* __restrict__ x, const float* __restrict__ W1,
    const float* __restrict__ atts, const float* __restrict__ attd,
    __half* __restrict__ h1, float* __restrict__ as1, float* __restrict__ ad1,
    float* __restrict__ gblkmax,
    const int* __restrict__ ei, int* __restrict__ gcnt,
    int E, int N, int B, int chunk, int G){
  __shared__ float xs[128 * 128];   // 64 KB exactly (hist part reuses prefix)
  if (blockIdx.x >= G){
    // ---- histogram part ----
    int bid = blockIdx.x - G;
    int* hist = (int*)xs;           // first 512 ints
    for (int t = threadIdx.x; t < B; t += 256) hist[t] = 0;
    __syncthreads();
    int T = E + N;
    int lo = bid * chunk;
    int hi = min(lo + chunk, T);
    for (int i = lo + (int)threadIdx.x; i < hi; i += 256){
      int d = (i < E) ? ei[E + i] : (i - E);
      atomicAdd(&hist[d >> BSHIFT], 1);
    }
    __syncthreads();
    for (int t = threadIdx.x; t < B; t += 256) gcnt[bid * B + t] = hist[t];
    return;
  }
  // ---- GEMM part ----
  int n0 = blockIdx.x * 128;
  int t = threadIdx.x;
  {
    int row = t & 127;
    int kc = t >> 7;                // 0 or 1 (k-half)
    int n = n0 + row;
    const float4* x4 = (const float4*)x;
    #pragma unroll 4
    for (int i = 0; i < 16; ++i){
      float4 v = (n < N) ? x4[(size_t)n * 32 + kc * 16 + i]
                         : make_float4(0.f, 0.f, 0.f, 0.f);
      int k = kc * 64 + 4 * i;
      xs[(k + 0) * 128 + row] = v.x;
      xs[(k + 1) * 128 + row] = v.y;
      xs[(k + 2) * 128 + row] = v.z;
      xs[(k + 3) * 128 + row] = v.w;
    }
  }
  __syncthreads();
  int m = t & 15;                 // cols 8m..8m+7
  int rg = t >> 4;                // rows 8rg..8rg+7
  int rb = rg * 8;
  const float4* W14 = (const float4*)W1;
  float acc[8][8];
  #pragma unroll
  for (int r = 0; r < 8; ++r)
    #pragma unroll
    for (int c = 0; c < 8; ++c) acc[r][c] = 0.f;
  #pragma unroll 2
  for (int k = 0; k < 128; ++k){
    float4 w0 = W14[k * 32 + 2 * m];
    float4 w1 = W14[k * 32 + 2 * m + 1];
    float4 xa = *(const float4*)&xs[k * 128 + rb];
    float4 xb = *(const float4*)&xs[k * 128 + rb + 4];
    float xr[8] = {xa.x, xa.y, xa.z, xa.w, xb.x, xb.y, xb.z, xb.w};
    float wc[8] = {w0.x, w0.y, w0.z, w0.w, w1.x, w1.y, w1.z, w1.w};
    #pragma unroll
    for (int r = 0; r < 8; ++r)
      #pragma unroll
      for (int c = 0; c < 8; ++c)
        acc[r][c] = fmaf(xr[r], wc[c], acc[r][c]);
  }
  float4 av0 = ((const float4*)atts)[2 * m], av1 = ((const float4*)atts)[2 * m + 1];
  float4 dv0 = ((const float4*)attd)[2 * m], dv1 = ((const float4*)attd)[2 * m + 1];
  int h = m >> 2;                 // head of cols 8m..8m+7
  float lmax = -INFINITY;
  #pragma unroll
  for (int r = 0; r < 8; ++r){
    int n = n0 + rb + r;
    if (n < N){
      union { __half2 hh[4]; float4 f; } u;
      u.hh[0] = __floats2half2_rn(acc[r][0], acc[r][1]);
      u.hh[1] = __floats2half2_rn(acc[r][2], acc[r][3]);
      u.hh[2] = __floats2half2_rn(acc[r][4], acc[r][5]);
      u.hh[3] = __floats2half2_rn(acc[r][6], acc[r][7]);
      *(float4*)(h1 + (size_t)n * 128 + 8 * m) = u.f;
    }
    float s  = acc[r][0]*av0.x + acc[r][1]*av0.y + acc[r][2]*av0.z + acc[r][3]*av0.w
             + acc[r][4]*av1.x + acc[r][5]*av1.y + acc[r][6]*av1.z + acc[r][7]*av1.w;
    float dd = acc[r][0]*dv0.x + acc[r][1]*dv0.y + acc[r][2]*dv0.z + acc[r][3]*dv0.w
             + acc[r][4]*dv1.x + acc[r][5]*dv1.y + acc[r][6]*dv1.z + acc[r][7]*dv1.w;
    s  += __shfl_down(s, 1);  s  += __shfl_down(s, 2);
    dd += __shfl_down(dd, 1); dd += __shfl_down(dd, 2);
    lmax = fmaxf(lmax, s);
    if ((m & 3) == 0 && n < N){
      as1[n * 4 + h] = s;
      ad1[n * 4 + h] = dd;
    }
  }
  // per-block head max -> gblkmax[blk*4+h]  (reuse xs after all reads done)
  __syncthreads();
  if ((m & 3) == 0) xs[(m >> 2) * 16 + rg] = lmax;
  __syncthreads();
  if (t < 4){
    float mx = xs[t * 16];
    #pragma unroll
    for (int i = 1; i < 16; ++i) mx = fmaxf(mx, xs[t * 16 + i]);
    gblkmax[blockIdx.x * 4 + t] = mx;
  }
}

// Pass B1: one block per bucket — scan its 256 per-block counts -> local
// offsets + bucket total. Block 0 additionally reduces gblkmax -> asmaxf
// and inits h2mm (replaces the old k_btscan side duties).
__global__ void k_bprefix(const int* __restrict__ gcnt, int* __restrict__ ecur,
                          int* __restrict__ btot,
                          const float* __restrict__ gblkmax,
                          float* __restrict__ asmaxf, unsigned* __restrict__ h2mm,
                          int B, int G4){
  __shared__ int ws[4];
  __shared__ unsigned smenc[4];
  int b = blockIdx.x;
  int t = threadIdx.x;            // = source block id
  int v = gcnt[t * B + b];
  int lane = t & 63, wid = t >> 6;
  int x = v;
  #pragma unroll
  for (int off = 1; off < 64; off <<= 1){
    int tmp = __shfl_up(x, off, 64);
    if (lane >= off) x += tmp;
  }
  if (lane == 63) ws[wid] = x;
  if (t < 4) smenc[t] = 0u;
  __syncthreads();
  if (t == 0){
    int s = 0;
    #pragma unroll
    for (int i = 0; i < 4; ++i){ int tmp = ws[i]; ws[i] = s; s += tmp; }
  }
  __syncthreads();
  int excl = ws[wid] + x - v;
  ecur[b * NB + t] = excl;
  if (t == 255) btot[b] = excl + v;
  if (b == 0){
    float lmax = -INFINITY;
    for (int i = t; i < G4; i += 256) lmax = fmaxf(lmax, gblkmax[i]);  // 256%4==0 -> fixed head
    atomicMax(&smenc[t & 3], fenc(lmax));
    __syncthreads();
    if (t < 4) asmaxf[t] = fdec(smenc[t]);
    if (t < 2) h2mm[t] = 0u;
  }
}

// Local LDS exclusive scan of btot[0..B) (B <= 512), 512 threads.
// On return sc[t] = sum(btot[0..t)).
__device__ __forceinline__ void local_btot_scan(const int* __restrict__ btot,
                                                int* sc, int* wsum8, int B){
  int tid = threadIdx.x;
  int lane = tid & 63, wid = tid >> 6;
  int v = (tid < B) ? btot[tid] : 0;
  int x = v;
  #pragma unroll
  for (int off = 1; off < 64; off <<= 1){
    int tmp = __shfl_up(x, off, 64);
    if (lane >= off) x += tmp;
  }
  if (lane == 63) wsum8[wid] = x;
  __syncthreads();
  if (tid == 0){
    int s = 0;
    #pragma unroll
    for (int i = 0; i < 8; ++i){ int tmp = wsum8[i]; wsum8[i] = s; s += tmp; }
  }
  __syncthreads();
  sc[tid] = wsum8[wid] + x - v;
  __syncthreads();
}

// Pass C: scatter packed (dloc,src) into bucket-partitioned ebuf (4B/edge).
// Computes bucket starts locally (no k_btscan dependency). 512 threads.
__global__ __launch_bounds__(512) void k_bscatter(
    const int* __restrict__ ei, const int* __restrict__ ecur,
    const int* __restrict__ btot, unsigned* __restrict__ ebuf,
    int E, int N, int B, int chunk){
  __shared__ int sc[512];
  __shared__ int wsum8[8];
  __shared__ int cur[512];
  local_btot_scan(btot, sc, wsum8, B);
  int tid = threadIdx.x;
  if (tid < B) cur[tid] = ecur[tid * NB + blockIdx.x] + sc[tid];
  __syncthreads();
  int T = E + N;
  int lo = blockIdx.x * chunk;
  int hi = min(lo + chunk, T);
  for (int i = lo + tid; i < hi; i += 512){
    int s, d;
    if (i < E){ s = ei[i]; d = ei[E + i]; } else { s = d = i - E; }
    int pos = atomicAdd(&cur[d >> BSHIFT], 1);
    ebuf[pos] = ((unsigned)(d & 127) << 25) | (unsigned)s;
  }
}

// Pass D: one block per bucket; LDS 128-dst hist + scan -> rs + final csr.
// Bucket range from local btot scan. 512 threads.
__global__ __launch_bounds__(512) void k_bfinal(
    const unsigned* __restrict__ ebuf, const int* __restrict__ btot,
    int* __restrict__ csr, int* __restrict__ rs,
    int N, int B, int T){
  __shared__ int sc[512];
  __shared__ int wsum8[8];
  __shared__ int hist[128];
  __shared__ int excl[128];
  local_btot_scan(btot, sc, wsum8, B);
  int b = blockIdx.x;
  int d0 = b << BSHIFT;
  int dcount = min(128, N - d0);
  int ebeg = sc[b];
  int eend = (b + 1 < B) ? sc[b + 1] : T;
  if (threadIdx.x < 128) hist[threadIdx.x] = 0;
  __syncthreads();
  for (int i = ebeg + (int)threadIdx.x; i < eend; i += 512)
    atomicAdd(&hist[ebuf[i] >> 25], 1);
  __syncthreads();
  if (threadIdx.x < 64){
    int l = threadIdx.x;
    int v0 = hist[l], v1 = hist[l + 64];
    int s0 = v0, s1 = v1;
    #pragma unroll
    for (int off = 1; off < 64; off <<= 1){
      int t0 = __shfl_up(s0, off, 64); if (l >= off) s0 += t0;
      int t1 = __shfl_up(s1, off, 64); if (l >= off) s1 += t1;
    }
    int tot0 = __shfl(s0, 63, 64);
    excl[l] = s0 - v0;
    excl[l + 64] = tot0 + s1 - v1;
  }
  __syncthreads();
  if (threadIdx.x < dcount) rs[d0 + threadIdx.x] = ebeg + excl[threadIdx.x];
  if (threadIdx.x < 128) hist[threadIdx.x] = excl[threadIdx.x];  // -> cursor
  if (b == 0 && threadIdx.x == 255) rs[N] = T;
  __syncthreads();
  for (int i = ebeg + (int)threadIdx.x; i < eend; i += 512){
    unsigned e = ebuf[i];
    int pos = ebeg + atomicAdd(&hist[e >> 25], 1);
    csr[pos] = (int)(e & 0x01FFFFFFu);
  }
}

// ---- Layer 1 aggregation: one wave per dst, 16 lanes per edge (8 fp16 ch/lane),
// 8 edges in flight (2 chains of 4) — the measured-fast round-8/12 structure.
// Softmax via global upper bound. Fuses /den, +bias, ELU, dot W2 -> h2[d].
// NO h2mm fusion: contended cross-XCD atomics per block cost ~240 us (b9-b13).
__global__ void k_agg1(const int* __restrict__ csr, const int* __restrict__ rs,
                       const float* __restrict__ as1, const float* __restrict__ ad1,
                       const float* __restrict__ asmaxf,
                       const float4* __restrict__ h1,
                       const float* __restrict__ bias1,
                       const float* __restrict__ W2, float* __restrict__ h2, int N){
  int wv = threadIdx.x >> 6;
  int lane = threadIdx.x & 63;
  int d = blockIdx.x * 4 + wv;
  if (d >= N) return;
  int g = lane >> 4;          // edge subgroup 0..3
  int m = lane & 15;          // channels 8m..8m+7
  int h = m >> 2;             // head
  float adh = ad1[d * 4 + h];
  float M = lrelu(asmaxf[h] + adh);
  int beg = rs[d], end = rs[d + 1];
  float den = 0.f;
  float a0=0.f,a1=0.f,a2=0.f,a3=0.f,a4=0.f,a5=0.f,a6=0.f,a7=0.f;
  int j = beg;
  for (; j + 8 <= end; j += 8){
    int sA = csr[j + g];
    int sB = csr[j + 4 + g];
    float eA = lrelu(as1[sA * 4 + h] + adh);
    float eB = lrelu(as1[sB * 4 + h] + adh);
    float pA = __expf(eA - M);
    float pB = __expf(eB - M);
    float4 rA = h1[(size_t)sA * 16 + m];
    float4 rB = h1[(size_t)sB * 16 + m];
    den += pA + pB;
    float2 cA0 = __half22float2(*(__half2*)&rA.x);
    float2 cA1 = __half22float2(*(__half2*)&rA.y);
    float2 cA2 = __half22float2(*(__half2*)&rA.z);
    float2 cA3 = __half22float2(*(__half2*)&rA.w);
    a0 = fmaf(pA, cA0.x, a0); a1 = fmaf(pA, cA0.y, a1);
    a2 = fmaf(pA, cA1.x, a2); a3 = fmaf(pA, cA1.y, a3);
    a4 = fmaf(pA, cA2.x, a4); a5 = fmaf(pA, cA2.y, a5);
    a6 = fmaf(pA, cA3.x, a6); a7 = fmaf(pA, cA3.y, a7);
    float2 cB0 = __half22float2(*(__half2*)&rB.x);
    float2 cB1 = __half22float2(*(__half2*)&rB.y);
    float2 cB2 = __half22float2(*(__half2*)&rB.z);
    float2 cB3 = __half22float2(*(__half2*)&rB.w);
    a0 = fmaf(pB, cB0.x, a0); a1 = fmaf(pB, cB0.y, a1);
    a2 = fmaf(pB, cB1.x, a2); a3 = fmaf(pB, cB1.y, a3);
    a4 = fmaf(pB, cB2.x, a4); a5 = fmaf(pB, cB2.y, a5);
    a6 = fmaf(pB, cB3.x, a6); a7 = fmaf(pB, cB3.y, a7);
  }
  for (; j < end; j += 4){
    int slot = j + g;
    bool v = slot < end;
    int s = csr[v ? slot : beg];
    float e = lrelu(as1[s * 4 + h] + adh);
    float p = v ? __expf(e - M) : 0.f;
    float4 raw = h1[(size_t)s * 16 + m];
    float2 c0 = __half22float2(*(__half2*)&raw.x);
    float2 c1 = __half22float2(*(__half2*)&raw.y);
    float2 c2 = __half22float2(*(__half2*)&raw.z);
    float2 c3 = __half22float2(*(__half2*)&raw.w);
    den += p;
    a0 = fmaf(p, c0.x, a0); a1 = fmaf(p, c0.y, a1);
    a2 = fmaf(p, c1.x, a2); a3 = fmaf(p, c1.y, a3);
    a4 = fmaf(p, c2.x, a4); a5 = fmaf(p, c2.y, a5);
    a6 = fmaf(p, c3.x, a6); a7 = fmaf(p, c3.y, a7);
  }
  #define CMB(v) v += __shfl_xor(v, 16); v += __shfl_xor(v, 32);
  CMB(a0) CMB(a1) CMB(a2) CMB(a3) CMB(a4) CMB(a5) CMB(a6) CMB(a7) CMB(den)
  #undef CMB
  float part = 0.f;
  if (lane < 16){
    float invden = 1.f / den;
    float4 b03 = ((const float4*)bias1)[2 * m];
    float4 b47 = ((const float4*)bias1)[2 * m + 1];
    float4 w03 = ((const float4*)W2)[2 * m];
    float4 w47 = ((const float4*)W2)[2 * m + 1];
    part  = elu1(a0 * invden + b03.x) * w03.x;
    part += elu1(a1 * invden + b03.y) * w03.y;
    part += elu1(a2 * invden + b03.z) * w03.z;
    part += elu1(a3 * invden + b03.w) * w03.w;
    part += elu1(a4 * invden + b47.x) * w47.x;
    part += elu1(a5 * invden + b47.y) * w47.y;
    part += elu1(a6 * invden + b47.z) * w47.z;
    part += elu1(a7 * invden + b47.w) * w47.w;
  }
  #pragma unroll
  for (int off = 8; off; off >>= 1) part += __shfl_down(part, off);
  if (lane == 0) h2[d] = part;
}

// global min/max of h2 (upper bound inputs for layer-2 softmax); few atomics.
__global__ void k_h2mm(const float* __restrict__ h2, unsigned* __restrict__ h2mm, int N){
  float mx = -INFINITY, mn = INFINITY;
  for (int i = blockIdx.x * blockDim.x + threadIdx.x; i < N; i += gridDim.x * blockDim.x){
    float v = h2[i];
    mx = fmaxf(mx, v); mn = fminf(mn, v);
  }
  #pragma unroll
  for (int off = 1; off < 64; off <<= 1){
    mx = fmaxf(mx, __shfl_xor(mx, off));
    mn = fminf(mn, __shfl_xor(mn, off));
  }
  if ((threadIdx.x & 63) == 0){
    atomicMax(&h2mm[0], fenc(mx));
    atomicMax(&h2mm[1], fenc(-mn));
  }
}

// Layer 2: 16 lanes per dst (4 dsts/wave), single pass (bound-stabilized).
__global__ void k_agg2(const int* __restrict__ csr, const int* __restrict__ rs,
                       const float* __restrict__ h2, const unsigned* __restrict__ h2mm,
                       const float* __restrict__ as2p, const float* __restrict__ ad2p,
                       const float* __restrict__ bias2, float* __restrict__ out, int N){
  int grp = threadIdx.x >> 4;     // 16 groups per block
  int l16 = threadIdx.x & 15;
  int d = blockIdx.x * 16 + grp;
  if (d >= N) return;
  float asc = as2p[0];
  float hmax = fdec(h2mm[0]), hmn = -fdec(h2mm[1]);
  float bound = (asc >= 0.f) ? asc * hmax : asc * hmn;
  float hd = h2[d] * ad2p[0];
  float M = lrelu(bound + hd);
  int beg = rs[d], end = rs[d + 1];
  float den = 0.f, acc = 0.f;
  for (int j = beg + l16; j < end; j += 16){
    float hs = h2[csr[j]];
    float p = __expf(lrelu(hs * asc + hd) - M);
    den += p;
    acc = fmaf(p, hs, acc);
  }
  #pragma unroll
  for (int off = 8; off; off >>= 1){
    den += __shfl_xor(den, off, 16);
    acc += __shfl_xor(acc, off, 16);
  }
  if (l16 == 0) out[d] = acc / den + bias2[0];
}

extern "C" void kernel_launch(void* const* d_in, const int* in_sizes, int n_in,
                              void* d_out, int out_size, void* d_ws, size_t ws_size,
                              hipStream_t stream){
  const float* x     = (const float*)d_in[0];
  const int*   ei    = (const int*)  d_in[1];
  const float* W1    = (const float*)d_in[2];
  const float* atts1 = (const float*)d_in[3];
  const float* attd1 = (const float*)d_in[4];
  const float* bias1 = (const float*)d_in[5];
  const float* W2    = (const float*)d_in[6];
  const float* atts2 = (const float*)d_in[7];
  const float* attd2 = (const float*)d_in[8];
  const float* bias2 = (const float*)d_in[9];

  int N = in_sizes[0] / 128;   // D = 128
  int E = in_sizes[1] / 2;
  int T = E + N;
  int B = (N + 127) >> BSHIFT;           // dst buckets of 128 (must be <= 512)
  int chunk = (T + NB - 1) / NB;
  int G = (N + 127) / 128;               // gemm blocks

  // workspace layout — EVERY sub-buffer 256-byte aligned (h1 is float4-accessed).
  uintptr_t base = (uintptr_t)d_ws;
  auto take = [&](size_t bytes) -> uintptr_t {
    base = (base + 255) & ~(uintptr_t)255;
    uintptr_t r = base;
    base += bytes;
    return r;
  };
  __half* h1     = (__half*)  take((size_t)N * 128 * 2);
  unsigned* ebuf = (unsigned*)take((size_t)T * 4);
  float*  as1    = (float*)   take((size_t)N * 4 * 4);
  float*  ad1    = (float*)   take((size_t)N * 4 * 4);
  float*  h2     = (float*)   take((size_t)N * 4);
  int*    gcnt   = (int*)     take((size_t)NB * B * 4);
  int*    ecur   = (int*)     take((size_t)NB * B * 4);
  int*    csr    = (int*)     take((size_t)T * 4);
  int*    rs     = (int*)     take((size_t)(N + 1) * 4);
  int*    btot   = (int*)     take((size_t)B * 4);
  float*  gblkmax= (float*)   take((size_t)G * 4 * 4);
  float*  asmaxf = (float*)   take(4 * 4);
  unsigned* h2mm = (unsigned*)take(2 * 4);

  k_gemm1_hist<<<G + NB, 256, 0, stream>>>(x, W1, atts1, attd1, h1, as1, ad1,
                                           gblkmax, ei, gcnt, E, N, B, chunk, G);
  k_bprefix <<<B, 256, 0, stream>>>(gcnt, ecur, btot, gblkmax, asmaxf, h2mm, B, G * 4);
  k_bscatter<<<NB, 512, 0, stream>>>(ei, ecur, btot, ebuf, E, N, B, chunk);
  k_bfinal  <<<B, 512, 0, stream>>>(ebuf, btot, csr, rs, N, B, T);
  k_agg1    <<<(N + 3) / 4, 256, 0, stream>>>(csr, rs, as1, ad1, asmaxf,
                                              (const float4*)h1, bias1, W2, h2, N);
  k_h2mm    <<<64, 256, 0, stream>>>(h2, h2mm, N);
  k_agg2    <<<(N + 15) / 16, 256, 0, stream>>>(csr, rs, h2, h2mm, atts2, attd2,
                                                bias2, (float*)d_out, N);
}

// Round 16
// 143.228 us; speedup vs baseline: 2.8020x; 1.0339x over previous
//
#include <hip/hip_runtime.h>
#include <hip/hip_fp16.h>
#include <stdint.h>

#define NEG_SLOPE 0.2f
#define BSHIFT 7          // bucket = dst >> 7  (128 dsts per bucket)
#define NB 256            // blocks in bucket hist/scatter passes

__device__ __forceinline__ float lrelu(float x){ return x > 0.f ? x : NEG_SLOPE * x; }
__device__ __forceinline__ float elu1(float x){ return x > 0.f ? x : expm1f(x); }
// float -> ordered uint encoding for atomicMax over signed floats
__device__ __forceinline__ unsigned fenc(float f){
  unsigned u = __float_as_uint(f);
  return (u & 0x80000000u) ? ~u : (u | 0x80000000u);
}
__device__ __forceinline__ float fdec(unsigned u){
  return (u & 0x80000000u) ? __uint_as_float(u & 0x7fffffffu) : __uint_as_float(~u);
}

// Fused: blocks [0,G) = h1 GEMM (128x128 tile, 8x8 reg tile);
//        blocks [G,G+NB) = per-block dst-bucket histogram (independent inputs).
__global__ __launch_bounds__(256) void k_gemm1_hist(
    const float* __restrict__ x, const float* __restrict__ W1,
    const float* __restrict__ atts, const float* __restrict__ attd,
    __half* __restrict__ h1, float* __restrict__ as1, float* __restrict__ ad1,
    float* __restrict__ gblkmax,
    const int* __restrict__ ei, int* __restrict__ gcnt,
    int E, int N, int B, int chunk, int G){
  __shared__ float xs[128 * 128];   // 64 KB exactly (hist part reuses prefix)
  if (blockIdx.x >= G){
    // ---- histogram part ----
    int bid = blockIdx.x - G;
    int* hist = (int*)xs;           // first 512 ints
    for (int t = threadIdx.x; t < B; t += 256) hist[t] = 0;
    __syncthreads();
    int T = E + N;
    int lo = bid * chunk;
    int hi = min(lo + chunk, T);
    for (int i = lo + (int)threadIdx.x; i < hi; i += 256){
      int d = (i < E) ? ei[E + i] : (i - E);
      atomicAdd(&hist[d >> BSHIFT], 1);
    }
    __syncthreads();
    for (int t = threadIdx.x; t < B; t += 256) gcnt[bid * B + t] = hist[t];
    return;
  }
  // ---- GEMM part ----
  int n0 = blockIdx.x * 128;
  int t = threadIdx.x;
  {
    int row = t & 127;
    int kc = t >> 7;                // 0 or 1 (k-half)
    int n = n0 + row;
    const float4* x4 = (const float4*)x;
    #pragma unroll 4
    for (int i = 0; i < 16; ++i){
      float4 v = (n < N) ? x4[(size_t)n * 32 + kc * 16 + i]
                         : make_float4(0.f, 0.f, 0.f, 0.f);
      int k = kc * 64 + 4 * i;
      xs[(k + 0) * 128 + row] = v.x;
      xs[(k + 1) * 128 + row] = v.y;
      xs[(k + 2) * 128 + row] = v.z;
      xs[(k + 3) * 128 + row] = v.w;
    }
  }
  __syncthreads();
  int m = t & 15;                 // cols 8m..8m+7
  int rg = t >> 4;                // rows 8rg..8rg+7
  int rb = rg * 8;
  const float4* W14 = (const float4*)W1;
  float acc[8][8];
  #pragma unroll
  for (int r = 0; r < 8; ++r)
    #pragma unroll
    for (int c = 0; c < 8; ++c) acc[r][c] = 0.f;
  #pragma unroll 2
  for (int k = 0; k < 128; ++k){
    float4 w0 = W14[k * 32 + 2 * m];
    float4 w1 = W14[k * 32 + 2 * m + 1];
    float4 xa = *(const float4*)&xs[k * 128 + rb];
    float4 xb = *(const float4*)&xs[k * 128 + rb + 4];
    float xr[8] = {xa.x, xa.y, xa.z, xa.w, xb.x, xb.y, xb.z, xb.w};
    float wc[8] = {w0.x, w0.y, w0.z, w0.w, w1.x, w1.y, w1.z, w1.w};
    #pragma unroll
    for (int r = 0; r < 8; ++r)
      #pragma unroll
      for (int c = 0; c < 8; ++c)
        acc[r][c] = fmaf(xr[r], wc[c], acc[r][c]);
  }
  float4 av0 = ((const float4*)atts)[2 * m], av1 = ((const float4*)atts)[2 * m + 1];
  float4 dv0 = ((const float4*)attd)[2 * m], dv1 = ((const float4*)attd)[2 * m + 1];
  int h = m >> 2;                 // head of cols 8m..8m+7
  float lmax = -INFINITY;
  #pragma unroll
  for (int r = 0; r < 8; ++r){
    int n = n0 + rb + r;
    if (n < N){
      union { __half2 hh[4]; float4 f; } u;
      u.hh[0] = __floats2half2_rn(acc[r][0], acc[r][1]);
      u.hh[1] = __floats2half2_rn(acc[r][2], acc[r][3]);
      u.hh[2] = __floats2half2_rn(acc[r][4], acc[r][5]);
      u.hh[3] = __floats2half2_rn(acc[r][6], acc[r][7]);
      *(float4*)(h1 + (size_t)n * 128 + 8 * m) = u.f;
    }
    float s  = acc[r][0]*av0.x + acc[r][1]*av0.y + acc[r][2]*av0.z + acc[r][3]*av0.w
             + acc[r][4]*av1.x + acc[r][5]*av1.y + acc[r][6]*av1.z + acc[r][7]*av1.w;
    float dd = acc[r][0]*dv0.x + acc[r][1]*dv0.y + acc[r][2]*dv0.z + acc[r][3]*dv0.w
             + acc[r][4]*dv1.x + acc[r][5]*dv1.y + acc[r][6]*dv1.z + acc[r][7]*dv1.w;
    s  += __shfl_down(s, 1);  s  += __shfl_down(s, 2);
    dd += __shfl_down(dd, 1); dd += __shfl_down(dd, 2);
    lmax = fmaxf(lmax, s);
    if ((m & 3) == 0 && n < N){
      as1[n * 4 + h] = s;
      ad1[n * 4 + h] = dd;
    }
  }
  // per-block head max -> gblkmax[blk*4+h]  (reuse xs after all reads done)
  __syncthreads();
  if ((m & 3) == 0) xs[(m >> 2) * 16 + rg] = lmax;
  __syncthreads();
  if (t < 4){
    float mx = xs[t * 16];
    #pragma unroll
    for (int i = 1; i < 16; ++i) mx = fmaxf(mx, xs[t * 16 + i]);
    gblkmax[blockIdx.x * 4 + t] = mx;
  }
}

// Pass B1: one block per bucket — scan its 256 per-block counts -> local
// offsets + bucket total. Block 0 additionally reduces gblkmax -> asmaxf.
__global__ void k_bprefix(const int* __restrict__ gcnt, int* __restrict__ ecur,
                          int* __restrict__ btot,
                          const float* __restrict__ gblkmax,
                          float* __restrict__ asmaxf,
                          int B, int G4){
  __shared__ int ws[4];
  __shared__ unsigned smenc[4];
  int b = blockIdx.x;
  int t = threadIdx.x;            // = source block id
  int v = gcnt[t * B + b];
  int lane = t & 63, wid = t >> 6;
  int x = v;
  #pragma unroll
  for (int off = 1; off < 64; off <<= 1){
    int tmp = __shfl_up(x, off, 64);
    if (lane >= off) x += tmp;
  }
  if (lane == 63) ws[wid] = x;
  if (t < 4) smenc[t] = 0u;
  __syncthreads();
  if (t == 0){
    int s = 0;
    #pragma unroll
    for (int i = 0; i < 4; ++i){ int tmp = ws[i]; ws[i] = s; s += tmp; }
  }
  __syncthreads();
  int excl = ws[wid] + x - v;
  ecur[b * NB + t] = excl;
  if (t == 255) btot[b] = excl + v;
  if (b == 0){
    float lmax = -INFINITY;
    for (int i = t; i < G4; i += 256) lmax = fmaxf(lmax, gblkmax[i]);  // 256%4==0 -> fixed head
    atomicMax(&smenc[t & 3], fenc(lmax));
    __syncthreads();
    if (t < 4) asmaxf[t] = fdec(smenc[t]);
  }
}

// Local LDS exclusive scan of btot[0..B) (B <= 512), 512 threads.
__device__ __forceinline__ void local_btot_scan(const int* __restrict__ btot,
                                                int* sc, int* wsum8, int B){
  int tid = threadIdx.x;
  int lane = tid & 63, wid = tid >> 6;
  int v = (tid < B) ? btot[tid] : 0;
  int x = v;
  #pragma unroll
  for (int off = 1; off < 64; off <<= 1){
    int tmp = __shfl_up(x, off, 64);
    if (lane >= off) x += tmp;
  }
  if (lane == 63) wsum8[wid] = x;
  __syncthreads();
  if (tid == 0){
    int s = 0;
    #pragma unroll
    for (int i = 0; i < 8; ++i){ int tmp = wsum8[i]; wsum8[i] = s; s += tmp; }
  }
  __syncthreads();
  sc[tid] = wsum8[wid] + x - v;
  __syncthreads();
}

// Pass C: scatter packed (dloc,src) into bucket-partitioned ebuf (4B/edge).
__global__ __launch_bounds__(512) void k_bscatter(
    const int* __restrict__ ei, const int* __restrict__ ecur,
    const int* __restrict__ btot, unsigned* __restrict__ ebuf,
    int E, int N, int B, int chunk){
  __shared__ int sc[512];
  __shared__ int wsum8[8];
  __shared__ int cur[512];
  local_btot_scan(btot, sc, wsum8, B);
  int tid = threadIdx.x;
  if (tid < B) cur[tid] = ecur[tid * NB + blockIdx.x] + sc[tid];
  __syncthreads();
  int T = E + N;
  int lo = blockIdx.x * chunk;
  int hi = min(lo + chunk, T);
  for (int i = lo + tid; i < hi; i += 512){
    int s, d;
    if (i < E){ s = ei[i]; d = ei[E + i]; } else { s = d = i - E; }
    int pos = atomicAdd(&cur[d >> BSHIFT], 1);
    ebuf[pos] = ((unsigned)(d & 127) << 25) | (unsigned)s;
  }
}

// Pass D: one block per bucket; LDS 128-dst hist + scan -> rs + final csr.
__global__ __launch_bounds__(512) void k_bfinal(
    const unsigned* __restrict__ ebuf, const int* __restrict__ btot,
    int* __restrict__ csr, int* __restrict__ rs,
    int N, int B, int T){
  __shared__ int sc[512];
  __shared__ int wsum8[8];
  __shared__ int hist[128];
  __shared__ int excl[128];
  local_btot_scan(btot, sc, wsum8, B);
  int b = blockIdx.x;
  int d0 = b << BSHIFT;
  int dcount = min(128, N - d0);
  int ebeg = sc[b];
  int eend = (b + 1 < B) ? sc[b + 1] : T;
  if (threadIdx.x < 128) hist[threadIdx.x] = 0;
  __syncthreads();
  for (int i = ebeg + (int)threadIdx.x; i < eend; i += 512)
    atomicAdd(&hist[ebuf[i] >> 25], 1);
  __syncthreads();
  if (threadIdx.x < 64){
    int l = threadIdx.x;
    int v0 = hist[l], v1 = hist[l + 64];
    int s0 = v0, s1 = v1;
    #pragma unroll
    for (int off = 1; off < 64; off <<= 1){
      int t0 = __shfl_up(s0, off, 64); if (l >= off) s0 += t0;
      int t1 = __shfl_up(s1, off, 64); if (l >= off) s1 += t1;
    }
    int tot0 = __shfl(s0, 63, 64);
    excl[l] = s0 - v0;
    excl[l + 64] = tot0 + s1 - v1;
  }
  __syncthreads();
  if (threadIdx.x < dcount) rs[d0 + threadIdx.x] = ebeg + excl[threadIdx.x];
  if (threadIdx.x < 128) hist[threadIdx.x] = excl[threadIdx.x];  // -> cursor
  if (b == 0 && threadIdx.x == 255) rs[N] = T;
  __syncthreads();
  for (int i = ebeg + (int)threadIdx.x; i < eend; i += 512){
    unsigned e = ebuf[i];
    int pos = ebeg + atomicAdd(&hist[e >> 25], 1);
    csr[pos] = (int)(e & 0x01FFFFFFu);
  }
}

// ---- Layer 1 aggregation: one wave per dst, 16 lanes per edge (8 fp16 ch/lane),
// 16 edges in flight (4 chains), clean prologue/epilogue (early return, no
// fusion, no shared mem) — first clean isolation of unroll width.
__global__ void k_agg1(const int* __restrict__ csr, const int* __restrict__ rs,
                       const float* __restrict__ as1, const float* __restrict__ ad1,
                       const float* __restrict__ asmaxf,
                       const float4* __restrict__ h1,
                       const float* __restrict__ bias1,
                       const float* __restrict__ W2, float* __restrict__ h2, int N){
  int wv = threadIdx.x >> 6;
  int lane = threadIdx.x & 63;
  int d = blockIdx.x * 4 + wv;
  if (d >= N) return;
  int g = lane >> 4;          // edge subgroup 0..3
  int m = lane & 15;          // channels 8m..8m+7
  int h = m >> 2;             // head
  float adh = ad1[d * 4 + h];
  float M = lrelu(asmaxf[h] + adh);
  int beg = rs[d], end = rs[d + 1];
  float den = 0.f;
  float a0=0.f,a1=0.f,a2=0.f,a3=0.f,a4=0.f,a5=0.f,a6=0.f,a7=0.f;
  int j = beg;
  for (; j + 16 <= end; j += 16){
    int sA = csr[j + g];
    int sB = csr[j + 4 + g];
    int sC = csr[j + 8 + g];
    int sD = csr[j + 12 + g];
    float pA = __expf(lrelu(as1[sA * 4 + h] + adh) - M);
    float pB = __expf(lrelu(as1[sB * 4 + h] + adh) - M);
    float pC = __expf(lrelu(as1[sC * 4 + h] + adh) - M);
    float pD = __expf(lrelu(as1[sD * 4 + h] + adh) - M);
    float4 rA = h1[(size_t)sA * 16 + m];
    float4 rB = h1[(size_t)sB * 16 + m];
    float4 rC = h1[(size_t)sC * 16 + m];
    float4 rD = h1[(size_t)sD * 16 + m];
    den += (pA + pB) + (pC + pD);
    {
      float2 c0 = __half22float2(*(__half2*)&rA.x);
      float2 c1 = __half22float2(*(__half2*)&rA.y);
      float2 c2 = __half22float2(*(__half2*)&rA.z);
      float2 c3 = __half22float2(*(__half2*)&rA.w);
      a0 = fmaf(pA, c0.x, a0); a1 = fmaf(pA, c0.y, a1);
      a2 = fmaf(pA, c1.x, a2); a3 = fmaf(pA, c1.y, a3);
      a4 = fmaf(pA, c2.x, a4); a5 = fmaf(pA, c2.y, a5);
      a6 = fmaf(pA, c3.x, a6); a7 = fmaf(pA, c3.y, a7);
    }
    {
      float2 c0 = __half22float2(*(__half2*)&rB.x);
      float2 c1 = __half22float2(*(__half2*)&rB.y);
      float2 c2 = __half22float2(*(__half2*)&rB.z);
      float2 c3 = __half22float2(*(__half2*)&rB.w);
      a0 = fmaf(pB, c0.x, a0); a1 = fmaf(pB, c0.y, a1);
      a2 = fmaf(pB, c1.x, a2); a3 = fmaf(pB, c1.y, a3);
      a4 = fmaf(pB, c2.x, a4); a5 = fmaf(pB, c2.y, a5);
      a6 = fmaf(pB, c3.x, a6); a7 = fmaf(pB, c3.y, a7);
    }
    {
      float2 c0 = __half22float2(*(__half2*)&rC.x);
      float2 c1 = __half22float2(*(__half2*)&rC.y);
      float2 c2 = __half22float2(*(__half2*)&rC.z);
      float2 c3 = __half22float2(*(__half2*)&rC.w);
      a0 = fmaf(pC, c0.x, a0); a1 = fmaf(pC, c0.y, a1);
      a2 = fmaf(pC, c1.x, a2); a3 = fmaf(pC, c1.y, a3);
      a4 = fmaf(pC, c2.x, a4); a5 = fmaf(pC, c2.y, a5);
      a6 = fmaf(pC, c3.x, a6); a7 = fmaf(pC, c3.y, a7);
    }
    {
      float2 c0 = __half22float2(*(__half2*)&rD.x);
      float2 c1 = __half22float2(*(__half2*)&rD.y);
      float2 c2 = __half22float2(*(__half2*)&rD.z);
      float2 c3 = __half22float2(*(__half2*)&rD.w);
      a0 = fmaf(pD, c0.x, a0); a1 = fmaf(pD, c0.y, a1);
      a2 = fmaf(pD, c1.x, a2); a3 = fmaf(pD, c1.y, a3);
      a4 = fmaf(pD, c2.x, a4); a5 = fmaf(pD, c2.y, a5);
      a6 = fmaf(pD, c3.x, a6); a7 = fmaf(pD, c3.y, a7);
    }
  }
  for (; j < end; j += 4){
    int slot = j + g;
    bool v = slot < end;
    int s = csr[v ? slot : beg];
    float e = lrelu(as1[s * 4 + h] + adh);
    float p = v ? __expf(e - M) : 0.f;
    float4 raw = h1[(size_t)s * 16 + m];
    float2 c0 = __half22float2(*(__half2*)&raw.x);
    float2 c1 = __half22float2(*(__half2*)&raw.y);
    float2 c2 = __half22float2(*(__half2*)&raw.z);
    float2 c3 = __half22float2(*(__half2*)&raw.w);
    den += p;
    a0 = fmaf(p, c0.x, a0); a1 = fmaf(p, c0.y, a1);
    a2 = fmaf(p, c1.x, a2); a3 = fmaf(p, c1.y, a3);
    a4 = fmaf(p, c2.x, a4); a5 = fmaf(p, c2.y, a5);
    a6 = fmaf(p, c3.x, a6); a7 = fmaf(p, c3.y, a7);
  }
  #define CMB(v) v += __shfl_xor(v, 16); v += __shfl_xor(v, 32);
  CMB(a0) CMB(a1) CMB(a2) CMB(a3) CMB(a4) CMB(a5) CMB(a6) CMB(a7) CMB(den)
  #undef CMB
  float part = 0.f;
  if (lane < 16){
    float invden = 1.f / den;
    float4 b03 = ((const float4*)bias1)[2 * m];
    float4 b47 = ((const float4*)bias1)[2 * m + 1];
    float4 w03 = ((const float4*)W2)[2 * m];
    float4 w47 = ((const float4*)W2)[2 * m + 1];
    part  = elu1(a0 * invden + b03.x) * w03.x;
    part += elu1(a1 * invden + b03.y) * w03.y;
    part += elu1(a2 * invden + b03.z) * w03.z;
    part += elu1(a3 * invden + b03.w) * w03.w;
    part += elu1(a4 * invden + b47.x) * w47.x;
    part += elu1(a5 * invden + b47.y) * w47.y;
    part += elu1(a6 * invden + b47.z) * w47.z;
    part += elu1(a7 * invden + b47.w) * w47.w;
  }
  #pragma unroll
  for (int off = 8; off; off >>= 1) part += __shfl_down(part, off);
  if (lane == 0) h2[d] = part;
}

// Layer 2: 16 lanes per dst (4 dsts/wave), single pass. No stabilizer:
// e = lrelu(as2*h2[s] + ad2*h2[d]) is O(1-10) << 88 (fp32 exp overflow);
// fminf(e,80) guards NaN without altering ratios in the non-overflow case.
__global__ void k_agg2(const int* __restrict__ csr, const int* __restrict__ rs,
                       const float* __restrict__ h2,
                       const float* __restrict__ as2p, const float* __restrict__ ad2p,
                       const float* __restrict__ bias2, float* __restrict__ out, int N){
  int grp = threadIdx.x >> 4;     // 16 groups per block
  int l16 = threadIdx.x & 15;
  int d = blockIdx.x * 16 + grp;
  if (d >= N) return;
  float asc = as2p[0];
  float hd = h2[d] * ad2p[0];
  int beg = rs[d], end = rs[d + 1];
  float den = 0.f, acc = 0.f;
  for (int j = beg + l16; j < end; j += 16){
    float hs = h2[csr[j]];
    float p = __expf(fminf(lrelu(hs * asc + hd), 80.f));
    den += p;
    acc = fmaf(p, hs, acc);
  }
  #pragma unroll
  for (int off = 8; off; off >>= 1){
    den += __shfl_xor(den, off, 16);
    acc += __shfl_xor(acc, off, 16);
  }
  if (l16 == 0) out[d] = acc / den + bias2[0];
}

extern "C" void kernel_launch(void* const* d_in, const int* in_sizes, int n_in,
                              void* d_out, int out_size, void* d_ws, size_t ws_size,
                              hipStream_t stream){
  const float* x     = (const float*)d_in[0];
  const int*   ei    = (const int*)  d_in[1];
  const float* W1    = (const float*)d_in[2];
  const float* atts1 = (const float*)d_in[3];
  const float* attd1 = (const float*)d_in[4];
  const float* bias1 = (const float*)d_in[5];
  const float* W2    = (const float*)d_in[6];
  const float* atts2 = (const float*)d_in[7];
  const float* attd2 = (const float*)d_in[8];
  const float* bias2 = (const float*)d_in[9];

  int N = in_sizes[0] / 128;   // D = 128
  int E = in_sizes[1] / 2;
  int T = E + N;
  int B = (N + 127) >> BSHIFT;           // dst buckets of 128 (must be <= 512)
  int chunk = (T + NB - 1) / NB;
  int G = (N + 127) / 128;               // gemm blocks

  // workspace layout — EVERY sub-buffer 256-byte aligned (h1 is float4-accessed).
  uintptr_t base = (uintptr_t)d_ws;
  auto take = [&](size_t bytes) -> uintptr_t {
    base = (base + 255) & ~(uintptr_t)255;
    uintptr_t r = base;
    base += bytes;
    return r;
  };
  __half* h1     = (__half*)  take((size_t)N * 128 * 2);
  unsigned* ebuf = (unsigned*)take((size_t)T * 4);
  float*  as1    = (float*)   take((size_t)N * 4 * 4);
  float*  ad1    = (float*)   take((size_t)N * 4 * 4);
  float*  h2     = (float*)   take((size_t)N * 4);
  int*    gcnt   = (int*)     take((size_t)NB * B * 4);
  int*    ecur   = (int*)     take((size_t)NB * B * 4);
  int*    csr    = (int*)     take((size_t)T * 4);
  int*    rs     = (int*)     take((size_t)(N + 1) * 4);
  int*    btot   = (int*)     take((size_t)B * 4);
  float*  gblkmax= (float*)   take((size_t)G * 4 * 4);
  float*  asmaxf = (float*)   take(4 * 4);

  k_gemm1_hist<<<G + NB, 256, 0, stream>>>(x, W1, atts1, attd1, h1, as1, ad1,
                                           gblkmax, ei, gcnt, E, N, B, chunk, G);
  k_bprefix <<<B, 256, 0, stream>>>(gcnt, ecur, btot, gblkmax, asmaxf, B, G * 4);
  k_bscatter<<<NB, 512, 0, stream>>>(ei, ecur, btot, ebuf, E, N, B, chunk);
  k_bfinal  <<<B, 512, 0, stream>>>(ebuf, btot, csr, rs, N, B, T);
  k_agg1    <<<(N + 3) / 4, 256, 0, stream>>>(csr, rs, as1, ad1, asmaxf,
                                              (const float4*)h1, bias1, W2, h2, N);
  k_agg2    <<<(N + 15) / 16, 256, 0, stream>>>(csr, rs, h2, atts2, attd2,
                                                bias2, (float*)d_out, N);
}

// Round 17
// 140.266 us; speedup vs baseline: 2.8612x; 1.0211x over previous
//
#include <hip/hip_runtime.h>
#include <hip/hip_fp16.h>
#include <stdint.h>

#define NEG_SLOPE 0.2f
#define BSHIFT 7          // bucket = dst >> 7  (128 dsts per bucket)
#define NB 256            // blocks in bucket hist/scatter passes

__device__ __forceinline__ float lrelu(float x){ return x > 0.f ? x : NEG_SLOPE * x; }
__device__ __forceinline__ float elu1(float x){ return x > 0.f ? x : expm1f(x); }
// float -> ordered uint encoding for atomicMax over signed floats
__device__ __forceinline__ unsigned fenc(float f){
  unsigned u = __float_as_uint(f);
  return (u & 0x80000000u) ? ~u : (u | 0x80000000u);
}
__device__ __forceinline__ float fdec(unsigned u){
  return (u & 0x80000000u) ? __uint_as_float(u & 0x7fffffffu) : __uint_as_float(~u);
}

// Fused: blocks [0,G) = h1 GEMM (128x128 tile, 8x8 reg tile);
//        blocks [G,G+NB) = per-block dst-bucket histogram (independent inputs).
__global__ __launch_bounds__(256) void k_gemm1_hist(
    const float* __restrict__ x, const float* __restrict__ W1,
    const float* __restrict__ atts, const float* __restrict__ attd,
    __half* __restrict__ h1, float* __restrict__ as1, float* __restrict__ ad1,
    float* __restrict__ gblkmax,
    const int* __restrict__ ei, int* __restrict__ gcnt,
    int E, int N, int B, int chunk, int G){
  __shared__ float xs[128 * 128];   // 64 KB exactly (hist part reuses prefix)
  if (blockIdx.x >= G){
    // ---- histogram part ----
    int bid = blockIdx.x - G;
    int* hist = (int*)xs;           // first 512 ints
    for (int t = threadIdx.x; t < B; t += 256) hist[t] = 0;
    __syncthreads();
    int T = E + N;
    int lo = bid * chunk;
    int hi = min(lo + chunk, T);
    for (int i = lo + (int)threadIdx.x; i < hi; i += 256){
      int d = (i < E) ? ei[E + i] : (i - E);
      atomicAdd(&hist[d >> BSHIFT], 1);
    }
    __syncthreads();
    for (int t = threadIdx.x; t < B; t += 256) gcnt[bid * B + t] = hist[t];
    return;
  }
  // ---- GEMM part ----
  int n0 = blockIdx.x * 128;
  int t = threadIdx.x;
  {
    int row = t & 127;
    int kc = t >> 7;                // 0 or 1 (k-half)
    int n = n0 + row;
    const float4* x4 = (const float4*)x;
    #pragma unroll 4
    for (int i = 0; i < 16; ++i){
      float4 v = (n < N) ? x4[(size_t)n * 32 + kc * 16 + i]
                         : make_float4(0.f, 0.f, 0.f, 0.f);
      int k = kc * 64 + 4 * i;
      xs[(k + 0) * 128 + row] = v.x;
      xs[(k + 1) * 128 + row] = v.y;
      xs[(k + 2) * 128 + row] = v.z;
      xs[(k + 3) * 128 + row] = v.w;
    }
  }
  __syncthreads();
  int m = t & 15;                 // cols 8m..8m+7
  int rg = t >> 4;                // rows 8rg..8rg+7
  int rb = rg * 8;
  const float4* W14 = (const float4*)W1;
  float acc[8][8];
  #pragma unroll
  for (int r = 0; r < 8; ++r)
    #pragma unroll
    for (int c = 0; c < 8; ++c) acc[r][c] = 0.f;
  #pragma unroll 2
  for (int k = 0; k < 128; ++k){
    float4 w0 = W14[k * 32 + 2 * m];
    float4 w1 = W14[k * 32 + 2 * m + 1];
    float4 xa = *(const float4*)&xs[k * 128 + rb];
    float4 xb = *(const float4*)&xs[k * 128 + rb + 4];
    float xr[8] = {xa.x, xa.y, xa.z, xa.w, xb.x, xb.y, xb.z, xb.w};
    float wc[8] = {w0.x, w0.y, w0.z, w0.w, w1.x, w1.y, w1.z, w1.w};
    #pragma unroll
    for (int r = 0; r < 8; ++r)
      #pragma unroll
      for (int c = 0; c < 8; ++c)
        acc[r][c] = fmaf(xr[r], wc[c], acc[r][c]);
  }
  float4 av0 = ((const float4*)atts)[2 * m], av1 = ((const float4*)atts)[2 * m + 1];
  float4 dv0 = ((const float4*)attd)[2 * m], dv1 = ((const float4*)attd)[2 * m + 1];
  int h = m >> 2;                 // head of cols 8m..8m+7
  float lmax = -INFINITY;
  #pragma unroll
  for (int r = 0; r < 8; ++r){
    int n = n0 + rb + r;
    if (n < N){
      union { __half2 hh[4]; float4 f; } u;
      u.hh[0] = __floats2half2_rn(acc[r][0], acc[r][1]);
      u.hh[1] = __floats2half2_rn(acc[r][2], acc[r][3]);
      u.hh[2] = __floats2half2_rn(acc[r][4], acc[r][5]);
      u.hh[3] = __floats2half2_rn(acc[r][6], acc[r][7]);
      *(float4*)(h1 + (size_t)n * 128 + 8 * m) = u.f;
    }
    float s  = acc[r][0]*av0.x + acc[r][1]*av0.y + acc[r][2]*av0.z + acc[r][3]*av0.w
             + acc[r][4]*av1.x + acc[r][5]*av1.y + acc[r][6]*av1.z + acc[r][7]*av1.w;
    float dd = acc[r][0]*dv0.x + acc[r][1]*dv0.y + acc[r][2]*dv0.z + acc[r][3]*dv0.w
             + acc[r][4]*dv1.x + acc[r][5]*dv1.y + acc[r][6]*dv1.z + acc[r][7]*dv1.w;
    s  += __shfl_down(s, 1);  s  += __shfl_down(s, 2);
    dd += __shfl_down(dd, 1); dd += __shfl_down(dd, 2);
    lmax = fmaxf(lmax, s);
    if ((m & 3) == 0 && n < N){
      as1[n * 4 + h] = s;
      ad1[n * 4 + h] = dd;
    }
  }
  // per-block head max -> gblkmax[blk*4+h]  (reuse xs after all reads done)
  __syncthreads();
  if ((m & 3) == 0) xs[(m >> 2) * 16 + rg] = lmax;
  __syncthreads();
  if (t < 4){
    float mx = xs[t * 16];
    #pragma unroll
    for (int i = 1; i < 16; ++i) mx = fmaxf(mx, xs[t * 16 + i]);
    gblkmax[blockIdx.x * 4 + t] = mx;
  }
}

// Pass B1: one block per bucket — scan its 256 per-block counts -> local
// offsets + bucket total. Block 0 additionally reduces gblkmax -> asmaxf.
__global__ void k_bprefix(const int* __restrict__ gcnt, int* __restrict__ ecur,
                          int* __restrict__ btot,
                          const float* __restrict__ gblkmax,
                          float* __restrict__ asmaxf,
                          int B, int G4){
  __shared__ int ws[4];
  __shared__ unsigned smenc[4];
  int b = blockIdx.x;
  int t = threadIdx.x;            // = source block id
  int v = gcnt[t * B + b];
  int lane = t & 63, wid = t >> 6;
  int x = v;
  #pragma unroll
  for (int off = 1; off < 64; off <<= 1){
    int tmp = __shfl_up(x, off, 64);
    if (lane >= off) x += tmp;
  }
  if (lane == 63) ws[wid] = x;
  if (t < 4) smenc[t] = 0u;
  __syncthreads();
  if (t == 0){
    int s = 0;
    #pragma unroll
    for (int i = 0; i < 4; ++i){ int tmp = ws[i]; ws[i] = s; s += tmp; }
  }
  __syncthreads();
  int excl = ws[wid] + x - v;
  ecur[b * NB + t] = excl;
  if (t == 255) btot[b] = excl + v;
  if (b == 0){
    float lmax = -INFINITY;
    for (int i = t; i < G4; i += 256) lmax = fmaxf(lmax, gblkmax[i]);  // 256%4==0 -> fixed head
    atomicMax(&smenc[t & 3], fenc(lmax));
    __syncthreads();
    if (t < 4) asmaxf[t] = fdec(smenc[t]);
  }
}

// Local LDS exclusive scan of btot[0..B) (B <= 512), 512 threads.
__device__ __forceinline__ void local_btot_scan(const int* __restrict__ btot,
                                                int* sc, int* wsum8, int B){
  int tid = threadIdx.x;
  int lane = tid & 63, wid = tid >> 6;
  int v = (tid < B) ? btot[tid] : 0;
  int x = v;
  #pragma unroll
  for (int off = 1; off < 64; off <<= 1){
    int tmp = __shfl_up(x, off, 64);
    if (lane >= off) x += tmp;
  }
  if (lane == 63) wsum8[wid] = x;
  __syncthreads();
  if (tid == 0){
    int s = 0;
    #pragma unroll
    for (int i = 0; i < 8; ++i){ int tmp = wsum8[i]; wsum8[i] = s; s += tmp; }
  }
  __syncthreads();
  sc[tid] = wsum8[wid] + x - v;
  __syncthreads();
}

// Pass C: scatter packed (dloc,src) into bucket-partitioned ebuf (4B/edge).
__global__ __launch_bounds__(512) void k_bscatter(
    const int* __restrict__ ei, const int* __restrict__ ecur,
    const int* __restrict__ btot, unsigned* __restrict__ ebuf,
    int E, int N, int B, int chunk){
  __shared__ int sc[512];
  __shared__ int wsum8[8];
  __shared__ int cur[512];
  local_btot_scan(btot, sc, wsum8, B);
  int tid = threadIdx.x;
  if (tid < B) cur[tid] = ecur[tid * NB + blockIdx.x] + sc[tid];
  __syncthreads();
  int T = E + N;
  int lo = blockIdx.x * chunk;
  int hi = min(lo + chunk, T);
  for (int i = lo + tid; i < hi; i += 512){
    int s, d;
    if (i < E){ s = ei[i]; d = ei[E + i]; } else { s = d = i - E; }
    int pos = atomicAdd(&cur[d >> BSHIFT], 1);
    ebuf[pos] = ((unsigned)(d & 127) << 25) | (unsigned)s;
  }
}

// Pass D: one block per bucket; LDS 128-dst hist + scan -> rs + final csr.
__global__ __launch_bounds__(512) void k_bfinal(
    const unsigned* __restrict__ ebuf, const int* __restrict__ btot,
    int* __restrict__ csr, int* __restrict__ rs,
    int N, int B, int T){
  __shared__ int sc[512];
  __shared__ int wsum8[8];
  __shared__ int hist[128];
  __shared__ int excl[128];
  local_btot_scan(btot, sc, wsum8, B);
  int b = blockIdx.x;
  int d0 = b << BSHIFT;
  int dcount = min(128, N - d0);
  int ebeg = sc[b];
  int eend = (b + 1 < B) ? sc[b + 1] : T;
  if (threadIdx.x < 128) hist[threadIdx.x] = 0;
  __syncthreads();
  for (int i = ebeg + (int)threadIdx.x; i < eend; i += 512)
    atomicAdd(&hist[ebuf[i] >> 25], 1);
  __syncthreads();
  if (threadIdx.x < 64){
    int l = threadIdx.x;
    int v0 = hist[l], v1 = hist[l + 64];
    int s0 = v0, s1 = v1;
    #pragma unroll
    for (int off = 1; off < 64; off <<= 1){
      int t0 = __shfl_up(s0, off, 64); if (l >= off) s0 += t0;
      int t1 = __shfl_up(s1, off, 64); if (l >= off) s1 += t1;
    }
    int tot0 = __shfl(s0, 63, 64);
    excl[l] = s0 - v0;
    excl[l + 64] = tot0 + s1 - v1;
  }
  __syncthreads();
  if (threadIdx.x < dcount) rs[d0 + threadIdx.x] = ebeg + excl[threadIdx.x];
  if (threadIdx.x < 128) hist[threadIdx.x] = excl[threadIdx.x];  // -> cursor
  if (b == 0 && threadIdx.x == 255) rs[N] = T;
  __syncthreads();
  for (int i = ebeg + (int)threadIdx.x; i < eend; i += 512){
    unsigned e = ebuf[i];
    int pos = ebeg + atomicAdd(&hist[e >> 25], 1);
    csr[pos] = (int)(e & 0x01FFFFFFu);
  }
}

// ---- Layer 1 aggregation: one wave per dst, 16 lanes per edge (8 fp16 ch/lane),
// 8 edges in flight (2 chains of 4) — the measured-fast structure (60.5 us,
// verified b8/b12/b14/b15; 16-edge is worse: 64 us b16, VGPR 36 vs 24).
// Softmax via global upper bound. Fuses /den, +bias, ELU, dot W2 -> h2[d].
__global__ void k_agg1(const int* __restrict__ csr, const int* __restrict__ rs,
                       const float* __restrict__ as1, const float* __restrict__ ad1,
                       const float* __restrict__ asmaxf,
                       const float4* __restrict__ h1,
                       const float* __restrict__ bias1,
                       const float* __restrict__ W2, float* __restrict__ h2, int N){
  int wv = threadIdx.x >> 6;
  int lane = threadIdx.x & 63;
  int d = blockIdx.x * 4 + wv;
  if (d >= N) return;
  int g = lane >> 4;          // edge subgroup 0..3
  int m = lane & 15;          // channels 8m..8m+7
  int h = m >> 2;             // head
  float adh = ad1[d * 4 + h];
  float M = lrelu(asmaxf[h] + adh);
  int beg = rs[d], end = rs[d + 1];
  float den = 0.f;
  float a0=0.f,a1=0.f,a2=0.f,a3=0.f,a4=0.f,a5=0.f,a6=0.f,a7=0.f;
  int j = beg;
  for (; j + 8 <= end; j += 8){
    int sA = csr[j + g];
    int sB = csr[j + 4 + g];
    float eA = lrelu(as1[sA * 4 + h] + adh);
    float eB = lrelu(as1[sB * 4 + h] + adh);
    float pA = __expf(eA - M);
    float pB = __expf(eB - M);
    float4 rA = h1[(size_t)sA * 16 + m];
    float4 rB = h1[(size_t)sB * 16 + m];
    den += pA + pB;
    float2 cA0 = __half22float2(*(__half2*)&rA.x);
    float2 cA1 = __half22float2(*(__half2*)&rA.y);
    float2 cA2 = __half22float2(*(__half2*)&rA.z);
    float2 cA3 = __half22float2(*(__half2*)&rA.w);
    a0 = fmaf(pA, cA0.x, a0); a1 = fmaf(pA, cA0.y, a1);
    a2 = fmaf(pA, cA1.x, a2); a3 = fmaf(pA, cA1.y, a3);
    a4 = fmaf(pA, cA2.x, a4); a5 = fmaf(pA, cA2.y, a5);
    a6 = fmaf(pA, cA3.x, a6); a7 = fmaf(pA, cA3.y, a7);
    float2 cB0 = __half22float2(*(__half2*)&rB.x);
    float2 cB1 = __half22float2(*(__half2*)&rB.y);
    float2 cB2 = __half22float2(*(__half2*)&rB.z);
    float2 cB3 = __half22float2(*(__half2*)&rB.w);
    a0 = fmaf(pB, cB0.x, a0); a1 = fmaf(pB, cB0.y, a1);
    a2 = fmaf(pB, cB1.x, a2); a3 = fmaf(pB, cB1.y, a3);
    a4 = fmaf(pB, cB2.x, a4); a5 = fmaf(pB, cB2.y, a5);
    a6 = fmaf(pB, cB3.x, a6); a7 = fmaf(pB, cB3.y, a7);
  }
  for (; j < end; j += 4){
    int slot = j + g;
    bool v = slot < end;
    int s = csr[v ? slot : beg];
    float e = lrelu(as1[s * 4 + h] + adh);
    float p = v ? __expf(e - M) : 0.f;
    float4 raw = h1[(size_t)s * 16 + m];
    float2 c0 = __half22float2(*(__half2*)&raw.x);
    float2 c1 = __half22float2(*(__half2*)&raw.y);
    float2 c2 = __half22float2(*(__half2*)&raw.z);
    float2 c3 = __half22float2(*(__half2*)&raw.w);
    den += p;
    a0 = fmaf(p, c0.x, a0); a1 = fmaf(p, c0.y, a1);
    a2 = fmaf(p, c1.x, a2); a3 = fmaf(p, c1.y, a3);
    a4 = fmaf(p, c2.x, a4); a5 = fmaf(p, c2.y, a5);
    a6 = fmaf(p, c3.x, a6); a7 = fmaf(p, c3.y, a7);
  }
  #define CMB(v) v += __shfl_xor(v, 16); v += __shfl_xor(v, 32);
  CMB(a0) CMB(a1) CMB(a2) CMB(a3) CMB(a4) CMB(a5) CMB(a6) CMB(a7) CMB(den)
  #undef CMB
  float part = 0.f;
  if (lane < 16){
    float invden = 1.f / den;
    float4 b03 = ((const float4*)bias1)[2 * m];
    float4 b47 = ((const float4*)bias1)[2 * m + 1];
    float4 w03 = ((const float4*)W2)[2 * m];
    float4 w47 = ((const float4*)W2)[2 * m + 1];
    part  = elu1(a0 * invden + b03.x) * w03.x;
    part += elu1(a1 * invden + b03.y) * w03.y;
    part += elu1(a2 * invden + b03.z) * w03.z;
    part += elu1(a3 * invden + b03.w) * w03.w;
    part += elu1(a4 * invden + b47.x) * w47.x;
    part += elu1(a5 * invden + b47.y) * w47.y;
    part += elu1(a6 * invden + b47.z) * w47.z;
    part += elu1(a7 * invden + b47.w) * w47.w;
  }
  #pragma unroll
  for (int off = 8; off; off >>= 1) part += __shfl_down(part, off);
  if (lane == 0) h2[d] = part;
}

// Layer 2: 16 lanes per dst (4 dsts/wave), single pass. No stabilizer:
// e = lrelu(as2*h2[s] + ad2*h2[d]) is O(1-10) << 88 (fp32 exp overflow);
// fminf(e,80) guards NaN without altering ratios in the non-overflow case.
__global__ void k_agg2(const int* __restrict__ csr, const int* __restrict__ rs,
                       const float* __restrict__ h2,
                       const float* __restrict__ as2p, const float* __restrict__ ad2p,
                       const float* __restrict__ bias2, float* __restrict__ out, int N){
  int grp = threadIdx.x >> 4;     // 16 groups per block
  int l16 = threadIdx.x & 15;
  int d = blockIdx.x * 16 + grp;
  if (d >= N) return;
  float asc = as2p[0];
  float hd = h2[d] * ad2p[0];
  int beg = rs[d], end = rs[d + 1];
  float den = 0.f, acc = 0.f;
  for (int j = beg + l16; j < end; j += 16){
    float hs = h2[csr[j]];
    float p = __expf(fminf(lrelu(hs * asc + hd), 80.f));
    den += p;
    acc = fmaf(p, hs, acc);
  }
  #pragma unroll
  for (int off = 8; off; off >>= 1){
    den += __shfl_xor(den, off, 16);
    acc += __shfl_xor(acc, off, 16);
  }
  if (l16 == 0) out[d] = acc / den + bias2[0];
}

extern "C" void kernel_launch(void* const* d_in, const int* in_sizes, int n_in,
                              void* d_out, int out_size, void* d_ws, size_t ws_size,
                              hipStream_t stream){
  const float* x     = (const float*)d_in[0];
  const int*   ei    = (const int*)  d_in[1];
  const float* W1    = (const float*)d_in[2];
  const float* atts1 = (const float*)d_in[3];
  const float* attd1 = (const float*)d_in[4];
  const float* bias1 = (const float*)d_in[5];
  const float* W2    = (const float*)d_in[6];
  const float* atts2 = (const float*)d_in[7];
  const float* attd2 = (const float*)d_in[8];
  const float* bias2 = (const float*)d_in[9];

  int N = in_sizes[0] / 128;   // D = 128
  int E = in_sizes[1] / 2;
  int T = E + N;
  int B = (N + 127) >> BSHIFT;           // dst buckets of 128 (must be <= 512)
  int chunk = (T + NB - 1) / NB;
  int G = (N + 127) / 128;               // gemm blocks

  // workspace layout — EVERY sub-buffer 256-byte aligned (h1 is float4-accessed).
  uintptr_t base = (uintptr_t)d_ws;
  auto take = [&](size_t bytes) -> uintptr_t {
    base = (base + 255) & ~(uintptr_t)255;
    uintptr_t r = base;
    base += bytes;
    return r;
  };
  __half* h1     = (__half*)  take((size_t)N * 128 * 2);
  unsigned* ebuf = (unsigned*)take((size_t)T * 4);
  float*  as1    = (float*)   take((size_t)N * 4 * 4);
  float*  ad1    = (float*)   take((size_t)N * 4 * 4);
  float*  h2     = (float*)   take((size_t)N * 4);
  int*    gcnt   = (int*)     take((size_t)NB * B * 4);
  int*    ecur   = (int*)     take((size_t)NB * B * 4);
  int*    csr    = (int*)     take((size_t)T * 4);
  int*    rs     = (int*)     take((size_t)(N + 1) * 4);
  int*    btot   = (int*)     take((size_t)B * 4);
  float*  gblkmax= (float*)   take((size_t)G * 4 * 4);
  float*  asmaxf = (float*)   take(4 * 4);

  k_gemm1_hist<<<G + NB, 256, 0, stream>>>(x, W1, atts1, attd1, h1, as1, ad1,
                                           gblkmax, ei, gcnt, E, N, B, chunk, G);
  k_bprefix <<<B, 256, 0, stream>>>(gcnt, ecur, btot, gblkmax, asmaxf, B, G * 4);
  k_bscatter<<<NB, 512, 0, stream>>>(ei, ecur, btot, ebuf, E, N, B, chunk);
  k_bfinal  <<<B, 512, 0, stream>>>(ebuf, btot, csr, rs, N, B, T);
  k_agg1    <<<(N + 3) / 4, 256, 0, stream>>>(csr, rs, as1, ad1, asmaxf,
                                              (const float4*)h1, bias1, W2, h2, N);
  k_agg2    <<<(N + 15) / 16, 256, 0, stream>>>(csr, rs, h2, atts2, attd2,
                                                bias2, (float*)d_out, N);
}